// Round 5
// baseline (10123.676 us; speedup 1.0000x reference)
//
#include <hip/hip_runtime.h>
#include <cstdint>
#include <cstddef>

// ---------------------------------------------------------------------------
// GCN(Cheb K=2, x2) -> 3-layer LSTM -> MLP head, MI355X gfx950.
// R9: R7/R8 (poll-at-top, C-in-regs, store-first) were ZERO delta -> the
//     falsifier fired: the cross-block agent-scope exchange IS the floor
//     (~10k cy/step of LLC visibility + spin round-trips vs ~900 cy of
//     compute). Fix: delete the exchange. One block per batch-group owns
//     ALL 256 h3 columns: 16 blocks x 512 thr, each wave computes 32 cols
//     (two 16-col groups). Recurrence state lives in LDS HS[2] only; one
//     lgkm barrier per step; no xbuf, no polls, no t>0 divergence (HS[0]
//     zeroed -> t=0 recurrence vs zeros is correct).
//     Per-lane regs: weights 96 frags = 384 + acc 32 + h2c 16 + misc ~ 470
//     < 512 unified cap at 2 waves/SIMD (weights bank to AGPRs per R6).
//     Predicted: lstmB 2447 -> 300-700us, MfmaUtil 1.66 -> 6-12, total
//     5358 -> ~3200-3700. Falsifier: VGPR=256 + scratch + dur >= 2ms ->
//     spill; R10 re-splits with K-split + LDS partial reduction.
// ---------------------------------------------------------------------------

#define T_DIM 32
#define F_DIMC 16
#define NNODE 15872
#define EDGES 200000
#define BATCH 256
#define SEQL 512
#define TN (T_DIM * NNODE)   // 507904
#define TE (T_DIM * EDGES)   // 6400000

typedef unsigned short ushortT;
typedef __bf16 bf16_t;
typedef bf16_t bf16x8 __attribute__((ext_vector_type(8)));
typedef float f32x4 __attribute__((ext_vector_type(4)));

__device__ __forceinline__ ushortT f2bf(float f) {
  union { float f; unsigned u; } v; v.f = f;
  unsigned u = v.u;
  u += 0x7fffu + ((u >> 16) & 1u);
  return (ushortT)(u >> 16);
}
__device__ __forceinline__ float fsig(float x) { return 1.0f / (1.0f + __expf(-x)); }
__device__ __forceinline__ float ftanh(float x) {
  float e = __expf(2.0f * x);
  return 1.0f - 2.0f / (e + 1.0f);
}
#define PIN(v) asm volatile("" : "+v"(v))

// Workgroup barrier WITHOUT the vmcnt(0) drain __syncthreads emits.
// LDS producer->consumer ordering needs lgkmcnt(0) only; global stores are
// allowed to stay in flight across timesteps (their consumers are later
// kernels).
__device__ __forceinline__ void bar_sync() {
  asm volatile("s_waitcnt lgkmcnt(0)\n\ts_barrier" ::: "memory");
  __builtin_amdgcn_sched_barrier(0);
}

// ---------------------------------------------------------------------------
// Weight prep: Wcat1 [256][128] = [wih1(62,pad2) | whh1(64)]
//              Wcat2 [512][192] = [wih2(64) | whh2(128)]
//              Wcat3 [1024][384] = [wih3(128) | whh3(256)]   (bf16, row = gate)
// ---------------------------------------------------------------------------
__global__ void k_wprep(const float* __restrict__ w1i, const float* __restrict__ w1h,
                        const float* __restrict__ w2i, const float* __restrict__ w2h,
                        const float* __restrict__ w3i, const float* __restrict__ w3h,
                        ushortT* __restrict__ Wcat) {
  int id = blockIdx.x * 256 + threadIdx.x;
  if (id >= 524288) return;
  float v;
  if (id < 32768) {
    int g = id >> 7, k = id & 127;
    v = (k < 62) ? w1i[g * 62 + k] : ((k >= 64) ? w1h[g * 64 + (k - 64)] : 0.0f);
  } else if (id < 131072) {
    int j = id - 32768; int g = j / 192, k = j % 192;
    v = (k < 64) ? w2i[g * 64 + k] : w2h[g * 128 + (k - 64)];
  } else {
    int j = id - 131072; int g = j / 384, k = j % 384;
    v = (k < 128) ? w3i[g * 128 + k] : w3h[g * 256 + (k - 128)];
  }
  Wcat[id] = f2bf(v);
}

// x [N][F][T] -> xt [T][N][F], LDS-tiled per node row
__global__ void k_transpose(const float* __restrict__ x, float* __restrict__ xt) {
  __shared__ float s[528];  // 16 x 33
  int n = blockIdx.x;
  int tid = threadIdx.x;
  for (int i = tid; i < 512; i += 256) {
    s[(i >> 5) * 33 + (i & 31)] = x[(size_t)n * 512 + i];
  }
  __syncthreads();
  for (int i = tid; i < 512; i += 256) {
    int t = i >> 4, f = i & 15;
    xt[((size_t)t * NNODE + n) * 16 + f] = s[f * 33 + t];
  }
}

// per-edge: deg[src] += w ; counts[dst] += 1
__global__ void k_degcount(const int* __restrict__ ei, const float* __restrict__ ew,
                           float* __restrict__ deg, int* __restrict__ counts) {
  int id = blockIdx.x * 256 + threadIdx.x;
  if (id >= TE) return;
  int t = id / EDGES, e = id % EDGES;
  int src = ei[(2 * t) * EDGES + e];
  int dst = ei[(2 * t + 1) * EDGES + e];
  atomicAdd(&deg[t * NNODE + src], ew[id]);
  atomicAdd(&counts[t * NNODE + dst], 1);
}

__global__ void k_dinv(float* __restrict__ deg) {
  int id = blockIdx.x * 256 + threadIdx.x;
  if (id >= TN) return;
  float d = deg[id];
  deg[id] = (d > 0.0f) ? rsqrtf(d) : 0.0f;
}

// block-local exclusive scan of counts (256-chunks), chunk totals out
__global__ void k_scanA(const int* __restrict__ counts, int* __restrict__ offs,
                        int* __restrict__ ctot) {
  __shared__ int s[256];
  int tid = threadIdx.x;
  int gid = blockIdx.x * 256 + tid;
  int v = counts[gid];
  s[tid] = v; __syncthreads();
  for (int off = 1; off < 256; off <<= 1) {
    int x = (tid >= off) ? s[tid - off] : 0;
    __syncthreads();
    s[tid] += x;
    __syncthreads();
  }
  offs[gid] = s[tid] - v;
  if (tid == 255) ctot[blockIdx.x] = s[255];
}

// single-block scan of 1984 chunk totals
__global__ void k_scanB(const int* __restrict__ ctot, int* __restrict__ cbase) {
  __shared__ int s[256];
  int tid = threadIdx.x;
  int carry = 0;
  for (int c = 0; c < 8; ++c) {
    int i = c * 256 + tid;
    int v = (i < 1984) ? ctot[i] : 0;
    s[tid] = v; __syncthreads();
    for (int off = 1; off < 256; off <<= 1) {
      int x = (tid >= off) ? s[tid - off] : 0;
      __syncthreads();
      s[tid] += x;
      __syncthreads();
    }
    if (i < 1984) cbase[i] = carry + s[tid] - v;
    int tot = s[255];
    __syncthreads();
    carry += tot;
  }
}

__global__ void k_scanC(int* __restrict__ offs, const int* __restrict__ cbase) {
  int id = blockIdx.x * 256 + threadIdx.x;
  if (id >= TN) return;
  offs[id] += cbase[id >> 8];
}

// scatter edges into CSR slots: csr_src[pos], csr_nrm[pos]
__global__ void k_fill(const int* __restrict__ ei, const float* __restrict__ ew,
                       const float* __restrict__ dinv, const int* __restrict__ offs,
                       int* __restrict__ fillc, int* __restrict__ csrs,
                       float* __restrict__ csrn) {
  int id = blockIdx.x * 256 + threadIdx.x;
  if (id >= TE) return;
  int t = id / EDGES, e = id % EDGES;
  int src = ei[(2 * t) * EDGES + e];
  int dst = ei[(2 * t + 1) * EDGES + e];
  int idx = t * NNODE + dst;
  int pos = offs[idx] + atomicAdd(&fillc[idx], 1);
  csrs[pos] = src;
  csrn[pos] = -dinv[t * NNODE + src] * ew[id] * dinv[idx];
}

__device__ __forceinline__ void fma4(float4& a, float sc, const float4 b) {
  a.x += sc * b.x; a.y += sc * b.y; a.z += sc * b.z; a.w += sc * b.w;
}

// gather (tx1) + combine: out = x@w0 + tx1@w1 + b [+leaky] ; mode1 writes xc bf16
__global__ void k_gc(const float* __restrict__ in, const int* __restrict__ offs,
                     const int* __restrict__ csrs, const float* __restrict__ csrn,
                     const float* __restrict__ w0, const float* __restrict__ w1,
                     const float* __restrict__ bias, float* __restrict__ outF,
                     ushortT* __restrict__ outX, int mode) {
  __shared__ float sw0[256], sw1[256], sb[16];
  int tid = threadIdx.x;
  sw0[tid] = w0[tid];
  sw1[tid] = w1[tid];
  if (tid < 16) sb[tid] = bias[tid];
  __syncthreads();
  int idx = blockIdx.x * 256 + tid;
  if (idx >= TN) return;
  int t = idx / NNODE, n = idx % NNODE;
  const float4* rowp = (const float4*)(in + (size_t)idx * 16);
  float4 x0 = rowp[0], x1 = rowp[1], x2 = rowp[2], x3 = rowp[3];
  float4 a0 = {0, 0, 0, 0}, a1 = {0, 0, 0, 0}, a2 = {0, 0, 0, 0}, a3 = {0, 0, 0, 0};
  int beg = offs[idx];
  int end = (idx == TN - 1) ? TE : offs[idx + 1];
  const float* base = in + (size_t)t * NNODE * 16;
  for (int p2 = beg; p2 < end; ++p2) {
    int s = csrs[p2];
    float nr = csrn[p2];
    const float4* rp = (const float4*)(base + (size_t)s * 16);
    fma4(a0, nr, rp[0]); fma4(a1, nr, rp[1]); fma4(a2, nr, rp[2]); fma4(a3, nr, rp[3]);
  }
  float xr[16], ar[16];
  *(float4*)&xr[0] = x0; *(float4*)&xr[4] = x1; *(float4*)&xr[8] = x2; *(float4*)&xr[12] = x3;
  *(float4*)&ar[0] = a0; *(float4*)&ar[4] = a1; *(float4*)&ar[8] = a2; *(float4*)&ar[12] = a3;
  float o[16];
#pragma unroll
  for (int j = 0; j < 16; ++j) o[j] = sb[j];
#pragma unroll
  for (int k = 0; k < 16; ++k) {
    float xv = xr[k], av = ar[k];
#pragma unroll
    for (int j = 0; j < 16; ++j) o[j] += xv * sw0[k * 16 + j] + av * sw1[k * 16 + j];
  }
  if (mode == 0) {
#pragma unroll
    for (int j = 0; j < 16; ++j) o[j] = (o[j] > 0.0f) ? o[j] : 0.01f * o[j];
    float4* op = (float4*)(outF + (size_t)idx * 16);
    op[0] = *(float4*)&o[0]; op[1] = *(float4*)&o[4];
    op[2] = *(float4*)&o[8]; op[3] = *(float4*)&o[12];
  } else {
    int bb = n / 62, ch = n % 62;
#pragma unroll
    for (int j = 0; j < 16; ++j)
      outX[((size_t)(bb * 512 + t * 16 + j)) * 64 + ch] = f2bf(o[j]);
  }
}

// ---------------------------------------------------------------------------
// LSTM stage A: layers 1+2. 16 blocks x 512 thr (8 waves), 1 block/CU.
// W1 (waves 0-3) + W2 (all) pinned; all frag indices compile-time.
// C1/C2 cell state in registers (pure per-thread state).
// h2(t) -> h2hist [g][t][16][128] bf16.
// ---------------------------------------------------------------------------
__global__ __launch_bounds__(512, 1) void k_lstmA(const ushortT* __restrict__ xc,
                                                  const ushortT* __restrict__ Wcat,
                                                  const float* __restrict__ b1g,
                                                  const float* __restrict__ b2g,
                                                  ushortT* __restrict__ h2hist) {
  __shared__ ushortT X1[2][16 * 72];
  __shared__ ushortT H1[2][16 * 72];
  __shared__ ushortT H2[2][16 * 136];
  int tid = threadIdx.x;
  int wv = tid >> 6, lane = tid & 63;
  int col = lane & 15, koff = (lane >> 4) * 8, m = lane & 15;
  int g = blockIdx.x;
  int bg = g * 16;
  const ushortT* W1 = Wcat;
  const ushortT* W2 = Wcat + 32768;

  bf16x8 w1r[4][4];
  if (wv < 4) {
#pragma unroll
    for (int q = 0; q < 4; ++q)
#pragma unroll
      for (int k = 0; k < 4; ++k) {
        w1r[q][k] = *reinterpret_cast<const bf16x8*>(
            &W1[(size_t)(q * 64 + wv * 16 + col) * 128 + k * 32 + koff]);
        PIN(w1r[q][k]);
      }
  }
  bf16x8 w2r[4][6];
#pragma unroll
  for (int q = 0; q < 4; ++q)
#pragma unroll
    for (int k = 0; k < 6; ++k) {
      w2r[q][k] = *reinterpret_cast<const bf16x8*>(
          &W2[(size_t)(q * 128 + wv * 16 + col) * 192 + k * 32 + koff]);
      PIN(w2r[q][k]);
    }
  float b1v[4] = {0, 0, 0, 0}, b2v[4];
  if (wv < 4) {
#pragma unroll
    for (int q = 0; q < 4; ++q) b1v[q] = b1g[q * 64 + wv * 16 + col];
  }
#pragma unroll
  for (int q = 0; q < 4; ++q) b2v[q] = b2g[q * 128 + wv * 16 + col];

  // cell states in registers: each (row,lc) cell touched by exactly 1 thread
  float c1r[4] = {0, 0, 0, 0};
  float c2r[4] = {0, 0, 0, 0};

  for (int i = tid; i < 2 * 16 * 72; i += 512) { X1[0][i] = 0; H1[0][i] = 0; }
  for (int i = tid; i < 2 * 16 * 136; i += 512) H2[0][i] = 0;
  __syncthreads();
  // prestage xc(t=0) into X1 parity 0 + prefetch xc(t=1) into regs (waves 4-5)
  uint4 xreg = {0, 0, 0, 0};
  {
    int tid2 = tid - 256;
    if (tid2 >= 0 && tid2 < 128) {
      int mm = tid2 >> 3, jj = (tid2 & 7) * 8;
      *(uint4*)&X1[0][mm * 72 + jj] =
          *(const uint4*)&xc[((size_t)(bg + mm) * 512 + 0) * 64 + jj];
      xreg = *(const uint4*)&xc[((size_t)(bg + mm) * 512 + 1) * 64 + jj];
    }
  }
  __syncthreads();

  for (int t = 0; t < 512; ++t) {
    int pr = t & 1, pw = 1 - pr;
    if (wv < 4) {
      // L1: K = 64 x | 64 h1 -> kt 0,1 from X1[pr], kt 2,3 from H1[pr]
      f32x4 acc[4] = {};
#pragma unroll
      for (int kt = 0; kt < 4; ++kt) {
        const ushortT* ap = (kt < 2) ? &X1[pr][m * 72 + kt * 32 + koff]
                                     : &H1[pr][m * 72 + (kt - 2) * 32 + koff];
        bf16x8 a = *reinterpret_cast<const bf16x8*>(ap);
#pragma unroll
        for (int q = 0; q < 4; ++q)
          acc[q] = __builtin_amdgcn_mfma_f32_16x16x32_bf16(a, w1r[q][kt], acc[q], 0, 0, 0);
      }
#pragma unroll
      for (int r = 0; r < 4; ++r) {
        int row = (lane >> 4) * 4 + r;
        int lc = wv * 16 + col;
        float gi = acc[0][r] + b1v[0];
        float gf = acc[1][r] + b1v[1];
        float gg = acc[2][r] + b1v[2];
        float go = acc[3][r] + b1v[3];
        float c = fsig(gf) * c1r[r] + fsig(gi) * ftanh(gg);
        float h = fsig(go) * ftanh(c);
        c1r[r] = c;
        H1[pw][row * 72 + lc] = f2bf(h);
      }
    } else {
      // waves 4-5: ds_write xc(t+1) from regs (loaded a full step ago),
      // then issue the load for xc(t+2).
      int tid2 = tid - 256;
      if (tid2 < 128) {
        int mm = tid2 >> 3, jj = (tid2 & 7) * 8;
        if (t + 1 < 512)
          *(uint4*)&X1[pw][mm * 72 + jj] = xreg;
        int tf = (t + 2 < 512) ? t + 2 : 511;
        xreg = *(const uint4*)&xc[((size_t)(bg + mm) * 512 + tf) * 64 + jj];
      }
    }
    bar_sync();
    // L2: K = 64 h1(t) | 128 h2(t-1) -> kt 0,1 from H1[pw], kt 2..5 from H2[pr]
    {
      f32x4 acc[4] = {};
#pragma unroll
      for (int kt = 0; kt < 6; ++kt) {
        const ushortT* ap = (kt < 2) ? &H1[pw][m * 72 + kt * 32 + koff]
                                     : &H2[pr][m * 136 + (kt - 2) * 32 + koff];
        bf16x8 a = *reinterpret_cast<const bf16x8*>(ap);
#pragma unroll
        for (int q = 0; q < 4; ++q)
          acc[q] = __builtin_amdgcn_mfma_f32_16x16x32_bf16(a, w2r[q][kt], acc[q], 0, 0, 0);
      }
#pragma unroll
      for (int r = 0; r < 4; ++r) {
        int row = (lane >> 4) * 4 + r;
        int lc = wv * 16 + col;
        float gi = acc[0][r] + b2v[0];
        float gf = acc[1][r] + b2v[1];
        float gg = acc[2][r] + b2v[2];
        float go = acc[3][r] + b2v[3];
        float c = fsig(gf) * c2r[r] + fsig(gi) * ftanh(gg);
        float h = fsig(go) * ftanh(c);
        c2r[r] = c;
        ushortT hb = f2bf(h);
        H2[pw][row * 136 + lc] = hb;
        h2hist[((size_t)(g * 512 + t) * 16 + row) * 128 + lc] = hb;
      }
    }
    bar_sync();
  }
}

// ---------------------------------------------------------------------------
// LSTM stage B: layer 3. 16 blocks x 512 thr, 1 block/CU. R9: ONE block owns
// all 256 h3 columns of its batch group -> recurrence via LDS only, no
// cross-block exchange. Each wave computes 32 cols (groups A: wv*16, B:
// 128+wv*16). Weights 96 frags/lane (384 regs, bank to AGPRs), all indices
// compile-time. One lgkm barrier per step. HS[0] zeroed -> uniform t loop.
// ---------------------------------------------------------------------------
__global__ __launch_bounds__(512, 1) void k_lstmB(const ushortT* __restrict__ h2hist,
                                                  const ushortT* __restrict__ Wcat,
                                                  const float* __restrict__ b3g,
                                                  ushortT* __restrict__ zbuf) {
  __shared__ ushortT HS[2][16 * 264];  // h3 state [16 rows][256 cols +8 pad]
  int tid = threadIdx.x;
  int wv = tid >> 6, lane = tid & 63;
  int col = lane & 15, koff = (lane >> 4) * 8, m = lane & 15;
  int g = blockIdx.x;
  int bg = g * 16;
  const ushortT* W3 = Wcat + 131072;

  int ca = wv * 16 + col;        // group A column (0..127)
  int cb = 128 + wv * 16 + col;  // group B column (128..255)

  // wHa/wHb: h2 input (K=128, 4 kt) ; wRa/wRb: h3 recurrence (K=256, 8 kt).
  // All register indices compile-time (rule #20).
  bf16x8 wHa[4][4], wHb[4][4], wRa[4][8], wRb[4][8];
#pragma unroll
  for (int q = 0; q < 4; ++q) {
    const ushortT* rwa = &W3[(size_t)(q * 256 + ca) * 384];
    const ushortT* rwb = &W3[(size_t)(q * 256 + cb) * 384];
#pragma unroll
    for (int j = 0; j < 4; ++j) {
      wHa[q][j] = *reinterpret_cast<const bf16x8*>(&rwa[j * 32 + koff]);
      wHb[q][j] = *reinterpret_cast<const bf16x8*>(&rwb[j * 32 + koff]);
      PIN(wHa[q][j]); PIN(wHb[q][j]);
    }
#pragma unroll
    for (int j = 0; j < 8; ++j) {
      wRa[q][j] = *reinterpret_cast<const bf16x8*>(&rwa[(4 + j) * 32 + koff]);
      wRb[q][j] = *reinterpret_cast<const bf16x8*>(&rwb[(4 + j) * 32 + koff]);
      PIN(wRa[q][j]); PIN(wRb[q][j]);
    }
  }
  float b3a[4], b3b[4];
#pragma unroll
  for (int q = 0; q < 4; ++q) {
    b3a[q] = b3g[q * 256 + ca];
    b3b[q] = b3g[q * 256 + cb];
  }

  float c3a[4] = {0, 0, 0, 0};  // cell state in registers
  float c3b[4] = {0, 0, 0, 0};

  for (int i = tid; i < 2 * 16 * 264; i += 512) HS[0][i] = 0;
  __syncthreads();

  // single-buffer register prefetch of h2hist fragments
  const ushortT* h2base = h2hist + (size_t)g * 512 * 16 * 128;
  bf16x8 h2c[4];
#pragma unroll
  for (int kt = 0; kt < 4; ++kt)
    h2c[kt] = *reinterpret_cast<const bf16x8*>(
        &h2base[(size_t)m * 128 + kt * 32 + koff]);

  for (int t = 0; t < 512; ++t) {
    int pr = t & 1, pw = 1 - pr;
    f32x4 aa[4] = {}, ab[4] = {};
    // phase A: h2(t) (prefetched) --------------------------------------------
#pragma unroll
    for (int kt = 0; kt < 4; ++kt) {
#pragma unroll
      for (int q = 0; q < 4; ++q) {
        aa[q] = __builtin_amdgcn_mfma_f32_16x16x32_bf16(h2c[kt], wHa[q][kt], aa[q], 0, 0, 0);
        ab[q] = __builtin_amdgcn_mfma_f32_16x16x32_bf16(h2c[kt], wHb[q][kt], ab[q], 0, 0, 0);
      }
    }
    // refill h2c with h2(t+1) — consumed next iteration
    {
      int tf = (t < 511) ? (t + 1) : t;
#pragma unroll
      for (int kt = 0; kt < 4; ++kt)
        h2c[kt] = *reinterpret_cast<const bf16x8*>(
            &h2base[((size_t)tf * 16 + m) * 128 + kt * 32 + koff]);
    }
    // phase B: h3(t-1) recurrence over all 256 cols from LDS ----------------
#pragma unroll
    for (int j = 0; j < 8; ++j) {
      bf16x8 a = *reinterpret_cast<const bf16x8*>(&HS[pr][m * 264 + j * 32 + koff]);
#pragma unroll
      for (int q = 0; q < 4; ++q) {
        aa[q] = __builtin_amdgcn_mfma_f32_16x16x32_bf16(a, wRa[q][j], aa[q], 0, 0, 0);
        ab[q] = __builtin_amdgcn_mfma_f32_16x16x32_bf16(a, wRb[q][j], ab[q], 0, 0, 0);
      }
    }
    // epilogue: gates -> c,h for both col groups; h -> LDS HS + zbuf
#pragma unroll
    for (int r = 0; r < 4; ++r) {
      int row = (lane >> 4) * 4 + r;
      {
        float gi = aa[0][r] + b3a[0];
        float gf = aa[1][r] + b3a[1];
        float gg = aa[2][r] + b3a[2];
        float go = aa[3][r] + b3a[3];
        float c = fsig(gf) * c3a[r] + fsig(gi) * ftanh(gg);
        float h = fsig(go) * ftanh(c);
        c3a[r] = c;
        ushortT hb = f2bf(h);
        HS[pw][row * 264 + ca] = hb;
        zbuf[((size_t)(bg + row) * 512 + t) * 256 + ca] = hb;
      }
      {
        float gi = ab[0][r] + b3b[0];
        float gf = ab[1][r] + b3b[1];
        float gg = ab[2][r] + b3b[2];
        float go = ab[3][r] + b3b[3];
        float c = fsig(gf) * c3b[r] + fsig(gi) * ftanh(gg);
        float h = fsig(go) * ftanh(c);
        c3b[r] = c;
        ushortT hb = f2bf(h);
        HS[pw][row * 264 + cb] = hb;
        zbuf[((size_t)(bg + row) * 512 + t) * 256 + cb] = hb;
      }
    }
    bar_sync();  // HS[pw] writes visible before next step's HS[pr] reads
  }
}

// ---------------------------------------------------------------------------
// fc1: split-K MFMA. grid (kb=64, nb=4); block computes [256m x 64n] partial
// over a 2048-K chunk; W transposed fp32->bf16 through LDS.
// ---------------------------------------------------------------------------
__global__ __launch_bounds__(256) void k_fc1(const ushortT* __restrict__ zbuf,
                                             const float* __restrict__ w,
                                             float* __restrict__ part) {
  __shared__ ushortT As[256 * 40];
  __shared__ ushortT Bs[64 * 40];
  int tid = threadIdx.x;
  int kb = blockIdx.x;  // 0..63
  int nb = blockIdx.y;  // 0..3
  int wv = tid >> 6, lane = tid & 63;
  int col = lane & 15, koff = (lane >> 4) * 8;
  int k0base = kb * 2048;
  f32x4 acc[4][4] = {};
  for (int kt = 0; kt < 64; ++kt) {
    int k0 = k0base + kt * 32;
    {
      const uint4* src = (const uint4*)(zbuf + (size_t)tid * 131072 + k0);
      uint4* dst = (uint4*)(As + tid * 40);
      dst[0] = src[0]; dst[1] = src[1]; dst[2] = src[2]; dst[3] = src[3];
    }
    {
      int kk = tid >> 3, j0 = (tid & 7) * 8;
      const float* srcw = w + (size_t)(k0 + kk) * 256 + nb * 64 + j0;
#pragma unroll
      for (int jj = 0; jj < 8; ++jj) Bs[(j0 + jj) * 40 + kk] = f2bf(srcw[jj]);
    }
    __syncthreads();
    bf16x8 bfr[4];
#pragma unroll
    for (int nt = 0; nt < 4; ++nt)
      bfr[nt] = *reinterpret_cast<const bf16x8*>(&Bs[(nt * 16 + col) * 40 + koff]);
#pragma unroll
    for (int mt = 0; mt < 4; ++mt) {
      bf16x8 afr = *reinterpret_cast<const bf16x8*>(&As[(wv * 64 + mt * 16 + col) * 40 + koff]);
#pragma unroll
      for (int nt = 0; nt < 4; ++nt)
        acc[mt][nt] = __builtin_amdgcn_mfma_f32_16x16x32_bf16(afr, bfr[nt], acc[mt][nt], 0, 0, 0);
    }
    __syncthreads();
  }
#pragma unroll
  for (int mt = 0; mt < 4; ++mt)
#pragma unroll
    for (int nt = 0; nt < 4; ++nt)
#pragma unroll
      for (int r = 0; r < 4; ++r) {
        int m = wv * 64 + mt * 16 + (lane >> 4) * 4 + r;
        int n = nb * 64 + nt * 16 + col;
        part[(size_t)kb * 65536 + m * 256 + n] = acc[mt][nt][r];
      }
}

__global__ void k_fc1red(const float* __restrict__ part, const float* __restrict__ b,
                         float* __restrict__ out) {
  int id = blockIdx.x * 256 + threadIdx.x;
  if (id >= 65536) return;
  float s = 0.0f;
  for (int kb = 0; kb < 64; ++kb) s += part[(size_t)kb * 65536 + id];
  s += b[id & 255];
  out[id] = fmaxf(s, 0.0f);
}

__global__ void k_fcv(const float* __restrict__ in, const float* __restrict__ w,
                      const float* __restrict__ b, float* __restrict__ out,
                      int K, int Nn, int doRelu) {
  int id = blockIdx.x * 256 + threadIdx.x;
  int m = id / Nn, n = id % Nn;
  float s = b[n];
  for (int k = 0; k < K; ++k) s += in[m * K + k] * w[k * Nn + n];
  if (doRelu) s = fmaxf(s, 0.0f);
  out[id] = s;
}

// ---------------------------------------------------------------------------
extern "C" void kernel_launch(void* const* d_in, const int* in_sizes, int n_in,
                              void* d_out, int out_size, void* d_ws, size_t ws_size,
                              hipStream_t stream) {
  (void)in_sizes; (void)n_in; (void)out_size; (void)ws_size;
  const float* x    = (const float*)d_in[0];
  const int* ei     = (const int*)d_in[1];
  const float* ew   = (const float*)d_in[2];
  const float* c1w0 = (const float*)d_in[4];
  const float* c1w1 = (const float*)d_in[5];
  const float* c1b  = (const float*)d_in[6];
  const float* c2w0 = (const float*)d_in[7];
  const float* c2w1 = (const float*)d_in[8];
  const float* c2b  = (const float*)d_in[9];
  const float* l1wi = (const float*)d_in[10];
  const float* l1wh = (const float*)d_in[11];
  const float* l1b  = (const float*)d_in[12];
  const float* l2wi = (const float*)d_in[13];
  const float* l2wh = (const float*)d_in[14];
  const float* l2b  = (const float*)d_in[15];
  const float* l3wi = (const float*)d_in[16];
  const float* l3wh = (const float*)d_in[17];
  const float* l3b  = (const float*)d_in[18];
  const float* fc1w = (const float*)d_in[19];
  const float* fc1b = (const float*)d_in[20];
  const float* fc2w = (const float*)d_in[21];
  const float* fc2b = (const float*)d_in[22];
  const float* fc3w = (const float*)d_in[23];
  const float* fc3b = (const float*)d_in[24];
  const float* fc4w = (const float*)d_in[25];
  const float* fc4b = (const float*)d_in[26];
  float* out = (float*)d_out;

  char* p = (char*)d_ws;
  auto alloc = [&](size_t bytes) { void* r = (void*)p; p += (bytes + 255) & ~(size_t)255; return r; };
  float* xt      = (float*)alloc(32505856);    // [T][N][16]  (reused as h2hist)
  float* h1buf   = (float*)alloc(32505856);    // conv1 out   (part of reuse window)
  float* dinv    = (float*)alloc(2031616);     // deg -> rsqrt in place
  int* counts    = (int*)alloc(2031616);
  int* offs      = (int*)alloc(2031616);
  int* fillc     = (int*)alloc(2031616);
  int* ctot      = (int*)alloc(8192);
  int* cbase     = (int*)alloc(8192);
  int* csrs      = (int*)alloc(25600000);
  float* csrn    = (float*)alloc(25600000);
  ushortT* xc    = (ushortT*)alloc(16777216);  // [B][512][64] bf16 (pad 62->64)
  ushortT* Wcat  = (ushortT*)alloc(1048576);
  ushortT* zbuf  = (ushortT*)alloc(67108864);  // [B][512][256] bf16
  float* part    = (float*)alloc(16777216);    // fc1 partials [64][256][256]
  float* fo1     = (float*)alloc(262144);
  float* fo2     = (float*)alloc(131072);
  float* fo3     = (float*)alloc(65536);
  // h2hist [16 groups][512 t][16 rows][128] bf16 = 33.5 MB; xt+h1buf (65 MB)
  // are dead after the k_gc pair -> reuse that region.
  ushortT* h2hist = (ushortT*)xt;

  hipMemsetAsync(dinv, 0, 2031616, stream);
  hipMemsetAsync(counts, 0, 2031616, stream);
  hipMemsetAsync(fillc, 0, 2031616, stream);
  hipMemsetAsync(xc, 0, 16777216, stream);

  k_wprep<<<2048, 256, 0, stream>>>(l1wi, l1wh, l2wi, l2wh, l3wi, l3wh, Wcat);
  k_transpose<<<15872, 256, 0, stream>>>(x, xt);
  k_degcount<<<25000, 256, 0, stream>>>(ei, ew, dinv, counts);
  k_dinv<<<1984, 256, 0, stream>>>(dinv);
  k_scanA<<<1984, 256, 0, stream>>>(counts, offs, ctot);
  k_scanB<<<1, 256, 0, stream>>>(ctot, cbase);
  k_scanC<<<1984, 256, 0, stream>>>(offs, cbase);
  k_fill<<<25000, 256, 0, stream>>>(ei, ew, dinv, offs, fillc, csrs, csrn);
  k_gc<<<1984, 256, 0, stream>>>(xt, offs, csrs, csrn, c1w0, c1w1, c1b, h1buf, nullptr, 0);
  k_gc<<<1984, 256, 0, stream>>>(h1buf, offs, csrs, csrn, c2w0, c2w1, c2b, nullptr, xc, 1);
  k_lstmA<<<16, 512, 0, stream>>>(xc, Wcat, l1b, l2b, h2hist);
  k_lstmB<<<16, 512, 0, stream>>>(h2hist, Wcat, l3b, zbuf);
  k_fc1<<<dim3(64, 4), 256, 0, stream>>>(zbuf, fc1w, part);
  k_fc1red<<<256, 256, 0, stream>>>(part, fc1b, fo1);
  k_fcv<<<128, 256, 0, stream>>>(fo1, fc2w, fc2b, fo2, 256, 128, 1);
  k_fcv<<<64, 256, 0, stream>>>(fo2, fc3w, fc3b, fo3, 128, 64, 1);
  k_fcv<<<4, 256, 0, stream>>>(fo3, fc4w, fc4b, out, 64, 4, 0);
}

// Round 6
// 5284.587 us; speedup vs baseline: 1.9157x; 1.9157x over previous
//
#include <hip/hip_runtime.h>
#include <cstdint>
#include <cstddef>

// ---------------------------------------------------------------------------
// GCN(Cheb K=2, x2) -> 3-layer LSTM -> MLP head, MI355X gfx950.
// R10: R9 regressed (7217us) exactly per falsifier: W3 residency needs
//     768KB regs > 512KB/CU pool (2048 per-lane regs, m69) -> spill. The
//     2-block split (245 regs/wave <= 256 cap at 8 waves) is the maximal
//     fitting config. REVERT lstmB to R8 structure.
//     New theory for R8's 4.75us/step: period = V + B with B~0.3us ->
//     V~4.4us, 10x a true LLC round trip. Cause: since R5 the loop has NO
//     vmcnt drain, so the agent-scope tag stores LINGER in the store path
//     until incidentally drained next step. LLVM's agent-release lowering
//     IS s_waitcnt vmcnt(0) — store completion = LLC visibility. One
//     block's drain is the partner's data.
//     Fix: split epilogue — xbuf tag stores, s_waitcnt vmcnt(0) (publish),
//     then HS/zbuf writes, then lgkm-only barrier.
//     Predicted: lstmB 2447 -> 600-1400us, total 5358 -> ~3500-4300.
//     Falsifier: lstmB >= 2.2ms -> visibility un-forceable -> R11 pivots
//     to lstmA||lstmB producer-consumer overlap.
// ---------------------------------------------------------------------------

#define T_DIM 32
#define F_DIMC 16
#define NNODE 15872
#define EDGES 200000
#define BATCH 256
#define SEQL 512
#define TN (T_DIM * NNODE)   // 507904
#define TE (T_DIM * EDGES)   // 6400000

typedef unsigned short ushortT;
typedef __bf16 bf16_t;
typedef bf16_t bf16x8 __attribute__((ext_vector_type(8)));
typedef float f32x4 __attribute__((ext_vector_type(4)));

__device__ __forceinline__ ushortT f2bf(float f) {
  union { float f; unsigned u; } v; v.f = f;
  unsigned u = v.u;
  u += 0x7fffu + ((u >> 16) & 1u);
  return (ushortT)(u >> 16);
}
__device__ __forceinline__ float fsig(float x) { return 1.0f / (1.0f + __expf(-x)); }
__device__ __forceinline__ float ftanh(float x) {
  float e = __expf(2.0f * x);
  return 1.0f - 2.0f / (e + 1.0f);
}
#define PIN(v) asm volatile("" : "+v"(v))

// Workgroup barrier WITHOUT the vmcnt(0) drain __syncthreads emits.
// LDS producer->consumer ordering needs lgkmcnt(0) only.
__device__ __forceinline__ void bar_sync() {
  asm volatile("s_waitcnt lgkmcnt(0)\n\ts_barrier" ::: "memory");
  __builtin_amdgcn_sched_barrier(0);
}

// ---------------------------------------------------------------------------
// Weight prep: Wcat1 [256][128] = [wih1(62,pad2) | whh1(64)]
//              Wcat2 [512][192] = [wih2(64) | whh2(128)]
//              Wcat3 [1024][384] = [wih3(128) | whh3(256)]   (bf16, row = gate)
// ---------------------------------------------------------------------------
__global__ void k_wprep(const float* __restrict__ w1i, const float* __restrict__ w1h,
                        const float* __restrict__ w2i, const float* __restrict__ w2h,
                        const float* __restrict__ w3i, const float* __restrict__ w3h,
                        ushortT* __restrict__ Wcat) {
  int id = blockIdx.x * 256 + threadIdx.x;
  if (id >= 524288) return;
  float v;
  if (id < 32768) {
    int g = id >> 7, k = id & 127;
    v = (k < 62) ? w1i[g * 62 + k] : ((k >= 64) ? w1h[g * 64 + (k - 64)] : 0.0f);
  } else if (id < 131072) {
    int j = id - 32768; int g = j / 192, k = j % 192;
    v = (k < 64) ? w2i[g * 64 + k] : w2h[g * 128 + (k - 64)];
  } else {
    int j = id - 131072; int g = j / 384, k = j % 384;
    v = (k < 128) ? w3i[g * 128 + k] : w3h[g * 256 + (k - 128)];
  }
  Wcat[id] = f2bf(v);
}

// x [N][F][T] -> xt [T][N][F], LDS-tiled per node row
__global__ void k_transpose(const float* __restrict__ x, float* __restrict__ xt) {
  __shared__ float s[528];  // 16 x 33
  int n = blockIdx.x;
  int tid = threadIdx.x;
  for (int i = tid; i < 512; i += 256) {
    s[(i >> 5) * 33 + (i & 31)] = x[(size_t)n * 512 + i];
  }
  __syncthreads();
  for (int i = tid; i < 512; i += 256) {
    int t = i >> 4, f = i & 15;
    xt[((size_t)t * NNODE + n) * 16 + f] = s[f * 33 + t];
  }
}

// per-edge: deg[src] += w ; counts[dst] += 1
__global__ void k_degcount(const int* __restrict__ ei, const float* __restrict__ ew,
                           float* __restrict__ deg, int* __restrict__ counts) {
  int id = blockIdx.x * 256 + threadIdx.x;
  if (id >= TE) return;
  int t = id / EDGES, e = id % EDGES;
  int src = ei[(2 * t) * EDGES + e];
  int dst = ei[(2 * t + 1) * EDGES + e];
  atomicAdd(&deg[t * NNODE + src], ew[id]);
  atomicAdd(&counts[t * NNODE + dst], 1);
}

__global__ void k_dinv(float* __restrict__ deg) {
  int id = blockIdx.x * 256 + threadIdx.x;
  if (id >= TN) return;
  float d = deg[id];
  deg[id] = (d > 0.0f) ? rsqrtf(d) : 0.0f;
}

// block-local exclusive scan of counts (256-chunks), chunk totals out
__global__ void k_scanA(const int* __restrict__ counts, int* __restrict__ offs,
                        int* __restrict__ ctot) {
  __shared__ int s[256];
  int tid = threadIdx.x;
  int gid = blockIdx.x * 256 + tid;
  int v = counts[gid];
  s[tid] = v; __syncthreads();
  for (int off = 1; off < 256; off <<= 1) {
    int x = (tid >= off) ? s[tid - off] : 0;
    __syncthreads();
    s[tid] += x;
    __syncthreads();
  }
  offs[gid] = s[tid] - v;
  if (tid == 255) ctot[blockIdx.x] = s[255];
}

// single-block scan of 1984 chunk totals
__global__ void k_scanB(const int* __restrict__ ctot, int* __restrict__ cbase) {
  __shared__ int s[256];
  int tid = threadIdx.x;
  int carry = 0;
  for (int c = 0; c < 8; ++c) {
    int i = c * 256 + tid;
    int v = (i < 1984) ? ctot[i] : 0;
    s[tid] = v; __syncthreads();
    for (int off = 1; off < 256; off <<= 1) {
      int x = (tid >= off) ? s[tid - off] : 0;
      __syncthreads();
      s[tid] += x;
      __syncthreads();
    }
    if (i < 1984) cbase[i] = carry + s[tid] - v;
    int tot = s[255];
    __syncthreads();
    carry += tot;
  }
}

__global__ void k_scanC(int* __restrict__ offs, const int* __restrict__ cbase) {
  int id = blockIdx.x * 256 + threadIdx.x;
  if (id >= TN) return;
  offs[id] += cbase[id >> 8];
}

// scatter edges into CSR slots: csr_src[pos], csr_nrm[pos]
__global__ void k_fill(const int* __restrict__ ei, const float* __restrict__ ew,
                       const float* __restrict__ dinv, const int* __restrict__ offs,
                       int* __restrict__ fillc, int* __restrict__ csrs,
                       float* __restrict__ csrn) {
  int id = blockIdx.x * 256 + threadIdx.x;
  if (id >= TE) return;
  int t = id / EDGES, e = id % EDGES;
  int src = ei[(2 * t) * EDGES + e];
  int dst = ei[(2 * t + 1) * EDGES + e];
  int idx = t * NNODE + dst;
  int pos = offs[idx] + atomicAdd(&fillc[idx], 1);
  csrs[pos] = src;
  csrn[pos] = -dinv[t * NNODE + src] * ew[id] * dinv[idx];
}

__device__ __forceinline__ void fma4(float4& a, float sc, const float4 b) {
  a.x += sc * b.x; a.y += sc * b.y; a.z += sc * b.z; a.w += sc * b.w;
}

// gather (tx1) + combine: out = x@w0 + tx1@w1 + b [+leaky] ; mode1 writes xc bf16
__global__ void k_gc(const float* __restrict__ in, const int* __restrict__ offs,
                     const int* __restrict__ csrs, const float* __restrict__ csrn,
                     const float* __restrict__ w0, const float* __restrict__ w1,
                     const float* __restrict__ bias, float* __restrict__ outF,
                     ushortT* __restrict__ outX, int mode) {
  __shared__ float sw0[256], sw1[256], sb[16];
  int tid = threadIdx.x;
  sw0[tid] = w0[tid];
  sw1[tid] = w1[tid];
  if (tid < 16) sb[tid] = bias[tid];
  __syncthreads();
  int idx = blockIdx.x * 256 + tid;
  if (idx >= TN) return;
  int t = idx / NNODE, n = idx % NNODE;
  const float4* rowp = (const float4*)(in + (size_t)idx * 16);
  float4 x0 = rowp[0], x1 = rowp[1], x2 = rowp[2], x3 = rowp[3];
  float4 a0 = {0, 0, 0, 0}, a1 = {0, 0, 0, 0}, a2 = {0, 0, 0, 0}, a3 = {0, 0, 0, 0};
  int beg = offs[idx];
  int end = (idx == TN - 1) ? TE : offs[idx + 1];
  const float* base = in + (size_t)t * NNODE * 16;
  for (int p2 = beg; p2 < end; ++p2) {
    int s = csrs[p2];
    float nr = csrn[p2];
    const float4* rp = (const float4*)(base + (size_t)s * 16);
    fma4(a0, nr, rp[0]); fma4(a1, nr, rp[1]); fma4(a2, nr, rp[2]); fma4(a3, nr, rp[3]);
  }
  float xr[16], ar[16];
  *(float4*)&xr[0] = x0; *(float4*)&xr[4] = x1; *(float4*)&xr[8] = x2; *(float4*)&xr[12] = x3;
  *(float4*)&ar[0] = a0; *(float4*)&ar[4] = a1; *(float4*)&ar[8] = a2; *(float4*)&ar[12] = a3;
  float o[16];
#pragma unroll
  for (int j = 0; j < 16; ++j) o[j] = sb[j];
#pragma unroll
  for (int k = 0; k < 16; ++k) {
    float xv = xr[k], av = ar[k];
#pragma unroll
    for (int j = 0; j < 16; ++j) o[j] += xv * sw0[k * 16 + j] + av * sw1[k * 16 + j];
  }
  if (mode == 0) {
#pragma unroll
    for (int j = 0; j < 16; ++j) o[j] = (o[j] > 0.0f) ? o[j] : 0.01f * o[j];
    float4* op = (float4*)(outF + (size_t)idx * 16);
    op[0] = *(float4*)&o[0]; op[1] = *(float4*)&o[4];
    op[2] = *(float4*)&o[8]; op[3] = *(float4*)&o[12];
  } else {
    int bb = n / 62, ch = n % 62;
#pragma unroll
    for (int j = 0; j < 16; ++j)
      outX[((size_t)(bb * 512 + t * 16 + j)) * 64 + ch] = f2bf(o[j]);
  }
}

// ---------------------------------------------------------------------------
// LSTM stage A: layers 1+2. 16 blocks x 512 thr (8 waves), 1 block/CU.
// W1 (waves 0-3) + W2 (all) pinned; all frag indices compile-time.
// C1/C2 cell state in registers. h2(t) -> h2hist [g][t][16][128] bf16.
// ---------------------------------------------------------------------------
__global__ __launch_bounds__(512, 1) void k_lstmA(const ushortT* __restrict__ xc,
                                                  const ushortT* __restrict__ Wcat,
                                                  const float* __restrict__ b1g,
                                                  const float* __restrict__ b2g,
                                                  ushortT* __restrict__ h2hist) {
  __shared__ ushortT X1[2][16 * 72];
  __shared__ ushortT H1[2][16 * 72];
  __shared__ ushortT H2[2][16 * 136];
  int tid = threadIdx.x;
  int wv = tid >> 6, lane = tid & 63;
  int col = lane & 15, koff = (lane >> 4) * 8, m = lane & 15;
  int g = blockIdx.x;
  int bg = g * 16;
  const ushortT* W1 = Wcat;
  const ushortT* W2 = Wcat + 32768;

  bf16x8 w1r[4][4];
  if (wv < 4) {
#pragma unroll
    for (int q = 0; q < 4; ++q)
#pragma unroll
      for (int k = 0; k < 4; ++k) {
        w1r[q][k] = *reinterpret_cast<const bf16x8*>(
            &W1[(size_t)(q * 64 + wv * 16 + col) * 128 + k * 32 + koff]);
        PIN(w1r[q][k]);
      }
  }
  bf16x8 w2r[4][6];
#pragma unroll
  for (int q = 0; q < 4; ++q)
#pragma unroll
    for (int k = 0; k < 6; ++k) {
      w2r[q][k] = *reinterpret_cast<const bf16x8*>(
          &W2[(size_t)(q * 128 + wv * 16 + col) * 192 + k * 32 + koff]);
      PIN(w2r[q][k]);
    }
  float b1v[4] = {0, 0, 0, 0}, b2v[4];
  if (wv < 4) {
#pragma unroll
    for (int q = 0; q < 4; ++q) b1v[q] = b1g[q * 64 + wv * 16 + col];
  }
#pragma unroll
  for (int q = 0; q < 4; ++q) b2v[q] = b2g[q * 128 + wv * 16 + col];

  // cell states in registers: each (row,lc) cell touched by exactly 1 thread
  float c1r[4] = {0, 0, 0, 0};
  float c2r[4] = {0, 0, 0, 0};

  for (int i = tid; i < 2 * 16 * 72; i += 512) { X1[0][i] = 0; H1[0][i] = 0; }
  for (int i = tid; i < 2 * 16 * 136; i += 512) H2[0][i] = 0;
  __syncthreads();
  // prestage xc(t=0) into X1 parity 0 + prefetch xc(t=1) into regs (waves 4-5)
  uint4 xreg = {0, 0, 0, 0};
  {
    int tid2 = tid - 256;
    if (tid2 >= 0 && tid2 < 128) {
      int mm = tid2 >> 3, jj = (tid2 & 7) * 8;
      *(uint4*)&X1[0][mm * 72 + jj] =
          *(const uint4*)&xc[((size_t)(bg + mm) * 512 + 0) * 64 + jj];
      xreg = *(const uint4*)&xc[((size_t)(bg + mm) * 512 + 1) * 64 + jj];
    }
  }
  __syncthreads();

  for (int t = 0; t < 512; ++t) {
    int pr = t & 1, pw = 1 - pr;
    if (wv < 4) {
      // L1: K = 64 x | 64 h1 -> kt 0,1 from X1[pr], kt 2,3 from H1[pr]
      f32x4 acc[4] = {};
#pragma unroll
      for (int kt = 0; kt < 4; ++kt) {
        const ushortT* ap = (kt < 2) ? &X1[pr][m * 72 + kt * 32 + koff]
                                     : &H1[pr][m * 72 + (kt - 2) * 32 + koff];
        bf16x8 a = *reinterpret_cast<const bf16x8*>(ap);
#pragma unroll
        for (int q = 0; q < 4; ++q)
          acc[q] = __builtin_amdgcn_mfma_f32_16x16x32_bf16(a, w1r[q][kt], acc[q], 0, 0, 0);
      }
#pragma unroll
      for (int r = 0; r < 4; ++r) {
        int row = (lane >> 4) * 4 + r;
        int lc = wv * 16 + col;
        float gi = acc[0][r] + b1v[0];
        float gf = acc[1][r] + b1v[1];
        float gg = acc[2][r] + b1v[2];
        float go = acc[3][r] + b1v[3];
        float c = fsig(gf) * c1r[r] + fsig(gi) * ftanh(gg);
        float h = fsig(go) * ftanh(c);
        c1r[r] = c;
        H1[pw][row * 72 + lc] = f2bf(h);
      }
    } else {
      // waves 4-5: ds_write xc(t+1) from regs (loaded a full step ago),
      // then issue the load for xc(t+2).
      int tid2 = tid - 256;
      if (tid2 < 128) {
        int mm = tid2 >> 3, jj = (tid2 & 7) * 8;
        if (t + 1 < 512)
          *(uint4*)&X1[pw][mm * 72 + jj] = xreg;
        int tf = (t + 2 < 512) ? t + 2 : 511;
        xreg = *(const uint4*)&xc[((size_t)(bg + mm) * 512 + tf) * 64 + jj];
      }
    }
    bar_sync();
    // L2: K = 64 h1(t) | 128 h2(t-1) -> kt 0,1 from H1[pw], kt 2..5 from H2[pr]
    {
      f32x4 acc[4] = {};
#pragma unroll
      for (int kt = 0; kt < 6; ++kt) {
        const ushortT* ap = (kt < 2) ? &H1[pw][m * 72 + kt * 32 + koff]
                                     : &H2[pr][m * 136 + (kt - 2) * 32 + koff];
        bf16x8 a = *reinterpret_cast<const bf16x8*>(ap);
#pragma unroll
        for (int q = 0; q < 4; ++q)
          acc[q] = __builtin_amdgcn_mfma_f32_16x16x32_bf16(a, w2r[q][kt], acc[q], 0, 0, 0);
      }
#pragma unroll
      for (int r = 0; r < 4; ++r) {
        int row = (lane >> 4) * 4 + r;
        int lc = wv * 16 + col;
        float gi = acc[0][r] + b2v[0];
        float gf = acc[1][r] + b2v[1];
        float gg = acc[2][r] + b2v[2];
        float go = acc[3][r] + b2v[3];
        float c = fsig(gf) * c2r[r] + fsig(gi) * ftanh(gg);
        float h = fsig(go) * ftanh(c);
        c2r[r] = c;
        ushortT hb = f2bf(h);
        H2[pw][row * 136 + lc] = hb;
        h2hist[((size_t)(g * 512 + t) * 16 + row) * 128 + lc] = hb;
      }
    }
    bar_sync();
  }
}

// ---------------------------------------------------------------------------
// LSTM stage B: layer 3. 32 blocks x 512 thr, 1 block/CU.
// Block (g,s) computes h3 cols [s*128,(s+1)*128). Weight frags wH/wO/wP,
// all register indices compile-time (rule #20). Poll loads at top of step.
// R10: epilogue split — tag stores, then s_waitcnt vmcnt(0) to PUBLISH
// them (agent-release lowering), then HS/zbuf writes, then lgkm barrier.
// ---------------------------------------------------------------------------
__global__ __launch_bounds__(512, 1) void k_lstmB(const ushortT* __restrict__ h2hist,
                                                  const ushortT* __restrict__ Wcat,
                                                  const float* __restrict__ b3g,
                                                  ushortT* __restrict__ zbuf,
                                                  uint32_t* __restrict__ xbuf) {
  __shared__ ushortT HS[2][16 * 136];
  __shared__ ushortT PS[2][16 * 136];
  int tid = threadIdx.x;
  int wv = tid >> 6, lane = tid & 63;
  int col = lane & 15, koff = (lane >> 4) * 8, m = lane & 15;
  int bx = blockIdx.x;
  int s = (bx >> 3) & 1;
  int g = (bx & 7) | ((bx >> 4) << 3);
  int ps = 1 - s;
  int bg = g * 16;
  const ushortT* W3 = Wcat + 131072;

  // wH: h2 k-blocks 0..3 ; wO: own h3 half ; wP: partner h3 half.
  // Runtime s only in ADDRESSES — all register indices compile-time.
  bf16x8 wH[4][4], wO[4][4], wP[4][4];
#pragma unroll
  for (int q = 0; q < 4; ++q) {
    const ushortT* rw = &W3[(size_t)(q * 256 + s * 128 + wv * 16 + col) * 384];
#pragma unroll
    for (int j = 0; j < 4; ++j) {
      wH[q][j] = *reinterpret_cast<const bf16x8*>(&rw[j * 32 + koff]);
      wO[q][j] = *reinterpret_cast<const bf16x8*>(&rw[(4 + s * 4 + j) * 32 + koff]);
      wP[q][j] = *reinterpret_cast<const bf16x8*>(&rw[(4 + ps * 4 + j) * 32 + koff]);
      PIN(wH[q][j]); PIN(wO[q][j]); PIN(wP[q][j]);
    }
  }
  float b3v[4];
#pragma unroll
  for (int q = 0; q < 4; ++q) b3v[q] = b3g[q * 256 + s * 128 + wv * 16 + col];

  float c3r[4] = {0, 0, 0, 0};  // cell state in registers

  for (int i = tid; i < 2 * 16 * 136; i += 512) HS[0][i] = 0;
  __syncthreads();

  // xbuf layout: [g][half][parity][16 rows][128 cols] u32
  uint32_t* myslot = xbuf + (((size_t)g * 2 + s) * 2) * 2048;
  const uint32_t* pslot = xbuf + (((size_t)g * 2 + ps) * 2) * 2048;

  // poll assignment: 512 threads x 4 words = 2048
  int prow = tid >> 5, pc0 = (tid & 31) * 4;

  // single-buffer register prefetch of h2hist fragments
  const ushortT* h2base = h2hist + (size_t)g * 512 * 16 * 128;
  bf16x8 h2c[4];
#pragma unroll
  for (int kt = 0; kt < 4; ++kt)
    h2c[kt] = *reinterpret_cast<const bf16x8*>(
        &h2base[(size_t)m * 128 + kt * 32 + koff]);

  for (int t = 0; t < 512; ++t) {
    int prt = t & 1, pw = 1 - prt;
    // issue partner poll loads FIRST — LLC latency hides under phaseA+own
    const uint32_t* pb = pslot + (size_t)prt * 2048 + prow * 128 + pc0;
    uint32_t v0 = 0, v1 = 0, v2 = 0, v3 = 0;
    if (t > 0) {
      v0 = __hip_atomic_load(pb + 0, __ATOMIC_RELAXED, __HIP_MEMORY_SCOPE_AGENT);
      v1 = __hip_atomic_load(pb + 1, __ATOMIC_RELAXED, __HIP_MEMORY_SCOPE_AGENT);
      v2 = __hip_atomic_load(pb + 2, __ATOMIC_RELAXED, __HIP_MEMORY_SCOPE_AGENT);
      v3 = __hip_atomic_load(pb + 3, __ATOMIC_RELAXED, __HIP_MEMORY_SCOPE_AGENT);
    }
    __builtin_amdgcn_sched_barrier(0);
    f32x4 acc[4] = {};
    // phase A: h2(t) (prefetched) --------------------------------------------
#pragma unroll
    for (int kt = 0; kt < 4; ++kt) {
#pragma unroll
      for (int q = 0; q < 4; ++q)
        acc[q] = __builtin_amdgcn_mfma_f32_16x16x32_bf16(h2c[kt], wH[q][kt], acc[q], 0, 0, 0);
    }
    // refill h2c with h2(t+1) — consumed next iteration
    {
      int tf = (t < 511) ? (t + 1) : t;
#pragma unroll
      for (int kt = 0; kt < 4; ++kt)
        h2c[kt] = *reinterpret_cast<const bf16x8*>(
            &h2base[((size_t)tf * 16 + m) * 128 + kt * 32 + koff]);
    }
    if (t > 0) {
      // own h3 half (from LDS HS)
#pragma unroll
      for (int j = 0; j < 4; ++j) {
        bf16x8 a = *reinterpret_cast<const bf16x8*>(&HS[prt][m * 136 + j * 32 + koff]);
#pragma unroll
        for (int q = 0; q < 4; ++q)
          acc[q] = __builtin_amdgcn_mfma_f32_16x16x32_bf16(a, wO[q][j], acc[q], 0, 0, 0);
      }
      // check tags (loads issued ~600cy ago)
      {
        uint32_t want = (uint32_t)t;
        while (((v0 >> 16) != want) | ((v1 >> 16) != want) |
               ((v2 >> 16) != want) | ((v3 >> 16) != want)) {
          v0 = __hip_atomic_load(pb + 0, __ATOMIC_RELAXED, __HIP_MEMORY_SCOPE_AGENT);
          v1 = __hip_atomic_load(pb + 1, __ATOMIC_RELAXED, __HIP_MEMORY_SCOPE_AGENT);
          v2 = __hip_atomic_load(pb + 2, __ATOMIC_RELAXED, __HIP_MEMORY_SCOPE_AGENT);
          v3 = __hip_atomic_load(pb + 3, __ATOMIC_RELAXED, __HIP_MEMORY_SCOPE_AGENT);
        }
        PS[prt][prow * 136 + pc0 + 0] = (ushortT)(v0 & 0xffffu);
        PS[prt][prow * 136 + pc0 + 1] = (ushortT)(v1 & 0xffffu);
        PS[prt][prow * 136 + pc0 + 2] = (ushortT)(v2 & 0xffffu);
        PS[prt][prow * 136 + pc0 + 3] = (ushortT)(v3 & 0xffffu);
      }
      bar_sync();
      // phase B: partner h3 half from PS
#pragma unroll
      for (int j = 0; j < 4; ++j) {
        bf16x8 a = *reinterpret_cast<const bf16x8*>(&PS[prt][m * 136 + j * 32 + koff]);
#pragma unroll
        for (int q = 0; q < 4; ++q)
          acc[q] = __builtin_amdgcn_mfma_f32_16x16x32_bf16(a, wP[q][j], acc[q], 0, 0, 0);
      }
    }
    // epilogue: gates -> c,h. Tag stores FIRST, then vmcnt(0) drain to
    // PUBLISH them at agent scope (one block's drain is the partner's
    // data), then HS/zbuf writes (stay in flight), then lgkm barrier.
    uint32_t* mw = myslot + (size_t)((t + 1) & 1) * 2048;
    ushortT hbs[4];
#pragma unroll
    for (int r = 0; r < 4; ++r) {
      int row = (lane >> 4) * 4 + r;
      int lc = wv * 16 + col;
      float gi = acc[0][r] + b3v[0];
      float gf = acc[1][r] + b3v[1];
      float gg = acc[2][r] + b3v[2];
      float go = acc[3][r] + b3v[3];
      float c = fsig(gf) * c3r[r] + fsig(gi) * ftanh(gg);
      float h = fsig(go) * ftanh(c);
      c3r[r] = c;
      hbs[r] = f2bf(h);
      __hip_atomic_store(mw + row * 128 + lc, ((uint32_t)(t + 1) << 16) | hbs[r],
                         __ATOMIC_RELAXED, __HIP_MEMORY_SCOPE_AGENT);
    }
    asm volatile("s_waitcnt vmcnt(0)" ::: "memory");
    __builtin_amdgcn_sched_barrier(0);
#pragma unroll
    for (int r = 0; r < 4; ++r) {
      int row = (lane >> 4) * 4 + r;
      int lc = wv * 16 + col;
      HS[pw][row * 136 + lc] = hbs[r];
      zbuf[((size_t)(bg + row) * 512 + t) * 256 + s * 128 + lc] = hbs[r];
    }
    bar_sync();  // HS[pw] write -> next step's own-phase read
  }
}

// ---------------------------------------------------------------------------
// fc1: split-K MFMA. grid (kb=64, nb=4); block computes [256m x 64n] partial
// over a 2048-K chunk; W transposed fp32->bf16 through LDS.
// ---------------------------------------------------------------------------
__global__ __launch_bounds__(256) void k_fc1(const ushortT* __restrict__ zbuf,
                                             const float* __restrict__ w,
                                             float* __restrict__ part) {
  __shared__ ushortT As[256 * 40];
  __shared__ ushortT Bs[64 * 40];
  int tid = threadIdx.x;
  int kb = blockIdx.x;  // 0..63
  int nb = blockIdx.y;  // 0..3
  int wv = tid >> 6, lane = tid & 63;
  int col = lane & 15, koff = (lane >> 4) * 8;
  int k0base = kb * 2048;
  f32x4 acc[4][4] = {};
  for (int kt = 0; kt < 64; ++kt) {
    int k0 = k0base + kt * 32;
    {
      const uint4* src = (const uint4*)(zbuf + (size_t)tid * 131072 + k0);
      uint4* dst = (uint4*)(As + tid * 40);
      dst[0] = src[0]; dst[1] = src[1]; dst[2] = src[2]; dst[3] = src[3];
    }
    {
      int kk = tid >> 3, j0 = (tid & 7) * 8;
      const float* srcw = w + (size_t)(k0 + kk) * 256 + nb * 64 + j0;
#pragma unroll
      for (int jj = 0; jj < 8; ++jj) Bs[(j0 + jj) * 40 + kk] = f2bf(srcw[jj]);
    }
    __syncthreads();
    bf16x8 bfr[4];
#pragma unroll
    for (int nt = 0; nt < 4; ++nt)
      bfr[nt] = *reinterpret_cast<const bf16x8*>(&Bs[(nt * 16 + col) * 40 + koff]);
#pragma unroll
    for (int mt = 0; mt < 4; ++mt) {
      bf16x8 afr = *reinterpret_cast<const bf16x8*>(&As[(wv * 64 + mt * 16 + col) * 40 + koff]);
#pragma unroll
      for (int nt = 0; nt < 4; ++nt)
        acc[mt][nt] = __builtin_amdgcn_mfma_f32_16x16x32_bf16(afr, bfr[nt], acc[mt][nt], 0, 0, 0);
    }
    __syncthreads();
  }
#pragma unroll
  for (int mt = 0; mt < 4; ++mt)
#pragma unroll
    for (int nt = 0; nt < 4; ++nt)
#pragma unroll
      for (int r = 0; r < 4; ++r) {
        int m = wv * 64 + mt * 16 + (lane >> 4) * 4 + r;
        int n = nb * 64 + nt * 16 + col;
        part[(size_t)kb * 65536 + m * 256 + n] = acc[mt][nt][r];
      }
}

__global__ void k_fc1red(const float* __restrict__ part, const float* __restrict__ b,
                         float* __restrict__ out) {
  int id = blockIdx.x * 256 + threadIdx.x;
  if (id >= 65536) return;
  float s = 0.0f;
  for (int kb = 0; kb < 64; ++kb) s += part[(size_t)kb * 65536 + id];
  s += b[id & 255];
  out[id] = fmaxf(s, 0.0f);
}

__global__ void k_fcv(const float* __restrict__ in, const float* __restrict__ w,
                      const float* __restrict__ b, float* __restrict__ out,
                      int K, int Nn, int doRelu) {
  int id = blockIdx.x * 256 + threadIdx.x;
  int m = id / Nn, n = id % Nn;
  float s = b[n];
  for (int k = 0; k < K; ++k) s += in[m * K + k] * w[k * Nn + n];
  if (doRelu) s = fmaxf(s, 0.0f);
  out[id] = s;
}

// ---------------------------------------------------------------------------
extern "C" void kernel_launch(void* const* d_in, const int* in_sizes, int n_in,
                              void* d_out, int out_size, void* d_ws, size_t ws_size,
                              hipStream_t stream) {
  (void)in_sizes; (void)n_in; (void)out_size; (void)ws_size;
  const float* x    = (const float*)d_in[0];
  const int* ei     = (const int*)d_in[1];
  const float* ew   = (const float*)d_in[2];
  const float* c1w0 = (const float*)d_in[4];
  const float* c1w1 = (const float*)d_in[5];
  const float* c1b  = (const float*)d_in[6];
  const float* c2w0 = (const float*)d_in[7];
  const float* c2w1 = (const float*)d_in[8];
  const float* c2b  = (const float*)d_in[9];
  const float* l1wi = (const float*)d_in[10];
  const float* l1wh = (const float*)d_in[11];
  const float* l1b  = (const float*)d_in[12];
  const float* l2wi = (const float*)d_in[13];
  const float* l2wh = (const float*)d_in[14];
  const float* l2b  = (const float*)d_in[15];
  const float* l3wi = (const float*)d_in[16];
  const float* l3wh = (const float*)d_in[17];
  const float* l3b  = (const float*)d_in[18];
  const float* fc1w = (const float*)d_in[19];
  const float* fc1b = (const float*)d_in[20];
  const float* fc2w = (const float*)d_in[21];
  const float* fc2b = (const float*)d_in[22];
  const float* fc3w = (const float*)d_in[23];
  const float* fc3b = (const float*)d_in[24];
  const float* fc4w = (const float*)d_in[25];
  const float* fc4b = (const float*)d_in[26];
  float* out = (float*)d_out;

  char* p = (char*)d_ws;
  auto alloc = [&](size_t bytes) { void* r = (void*)p; p += (bytes + 255) & ~(size_t)255; return r; };
  float* xt      = (float*)alloc(32505856);    // [T][N][16]  (reused as h2hist)
  float* h1buf   = (float*)alloc(32505856);    // conv1 out   (part of reuse window)
  float* dinv    = (float*)alloc(2031616);     // deg -> rsqrt in place
  int* counts    = (int*)alloc(2031616);
  int* offs      = (int*)alloc(2031616);
  int* fillc     = (int*)alloc(2031616);
  int* ctot      = (int*)alloc(8192);
  int* cbase     = (int*)alloc(8192);
  int* csrs      = (int*)alloc(25600000);
  float* csrn    = (float*)alloc(25600000);
  ushortT* xc    = (ushortT*)alloc(16777216);  // [B][512][64] bf16 (pad 62->64)
  ushortT* Wcat  = (ushortT*)alloc(1048576);
  ushortT* zbuf  = (ushortT*)alloc(67108864);  // [B][512][256] bf16
  float* part    = (float*)alloc(16777216);    // fc1 partials [64][256][256]
  float* fo1     = (float*)alloc(262144);
  float* fo2     = (float*)alloc(131072);
  float* fo3     = (float*)alloc(65536);
  uint32_t* xbuf = (uint32_t*)alloc(524288);   // [16][2][2 parity][2048] u32
  // h2hist [16 groups][512 t][16 rows][128] bf16 = 33.5 MB; xt+h1buf (65 MB)
  // are dead after the k_gc pair -> reuse that region.
  ushortT* h2hist = (ushortT*)xt;

  hipMemsetAsync(dinv, 0, 2031616, stream);
  hipMemsetAsync(counts, 0, 2031616, stream);
  hipMemsetAsync(fillc, 0, 2031616, stream);
  hipMemsetAsync(xc, 0, 16777216, stream);
  // xbuf needs no init: harness poisons d_ws with 0xAA -> tag 0xAAAA never
  // matches any live tag (1..512).

  k_wprep<<<2048, 256, 0, stream>>>(l1wi, l1wh, l2wi, l2wh, l3wi, l3wh, Wcat);
  k_transpose<<<15872, 256, 0, stream>>>(x, xt);
  k_degcount<<<25000, 256, 0, stream>>>(ei, ew, dinv, counts);
  k_dinv<<<1984, 256, 0, stream>>>(dinv);
  k_scanA<<<1984, 256, 0, stream>>>(counts, offs, ctot);
  k_scanB<<<1, 256, 0, stream>>>(ctot, cbase);
  k_scanC<<<1984, 256, 0, stream>>>(offs, cbase);
  k_fill<<<25000, 256, 0, stream>>>(ei, ew, dinv, offs, fillc, csrs, csrn);
  k_gc<<<1984, 256, 0, stream>>>(xt, offs, csrs, csrn, c1w0, c1w1, c1b, h1buf, nullptr, 0);
  k_gc<<<1984, 256, 0, stream>>>(h1buf, offs, csrs, csrn, c2w0, c2w1, c2b, nullptr, xc, 1);
  k_lstmA<<<16, 512, 0, stream>>>(xc, Wcat, l1b, l2b, h2hist);
  k_lstmB<<<32, 512, 0, stream>>>(h2hist, Wcat, l3b, zbuf, xbuf);
  k_fc1<<<dim3(64, 4), 256, 0, stream>>>(zbuf, fc1w, part);
  k_fc1red<<<256, 256, 0, stream>>>(part, fc1b, fo1);
  k_fcv<<<128, 256, 0, stream>>>(fo1, fc2w, fc2b, fo2, 256, 128, 1);
  k_fcv<<<64, 256, 0, stream>>>(fo2, fc3w, fc3b, fo3, 128, 64, 1);
  k_fcv<<<4, 256, 0, stream>>>(fo3, fc4w, fc4b, out, 64, 4, 0);
}

// Round 7
// 3614.234 us; speedup vs baseline: 2.8011x; 1.4622x over previous
//
#include <hip/hip_runtime.h>
#include <cstdint>
#include <cstddef>

// ---------------------------------------------------------------------------
// GCN(Cheb K=2, x2) -> 3-layer LSTM -> MLP head, MI355X gfx950.
// R11: R8/R10 proved the lstmB cross-block exchange cost (~4.4us/step) is
//     un-forceable (poll placement, C-in-regs, vmcnt publish: all null) and
//     R9 proved single-block weight residency is impossible (768KB > 512KB
//     register file/CU). Pivot per pre-committed falsifier: stop shaving
//     B's chain; OVERLAP lstmA with it. One kernel, 48 blocks: 16 A-role
//     (layers 1+2) + 32 B-role (layer 3). Dependency is per-(g,t): B's
//     step t needs only h2(t). A never waits on B; A's step (~2-3us) <
//     B's (4.6us) -> A stays ahead, B's rate unchanged, lstmA's entire
//     standalone duration (~1-1.5ms) vanishes from the wall clock.
//     Transport: self-validating tagged u32 (tag<<16|bf16, relaxed agent)
//     exactly like the working xbuf scheme -> no fences, immune to
//     cross-XCD L2 non-coherence. Full-depth h2x[g][512][2048] u32 (64MB)
//     aliased over dead xt/h1buf/dinv/counts, memset-0 between k_gc and
//     k_lstm (tags 1..512 can't collide with 0).
//     Predicted: fused k_lstm 2.4-2.7ms, total 5284 -> ~3900-4400us.
//     Falsifier: fused >= 3.2ms -> A is the feeder bottleneck -> R12
//     speeds A's step (merge L1/L2 epilogues, single barrier).
// ---------------------------------------------------------------------------

#define T_DIM 32
#define F_DIMC 16
#define NNODE 15872
#define EDGES 200000
#define BATCH 256
#define SEQL 512
#define TN (T_DIM * NNODE)   // 507904
#define TE (T_DIM * EDGES)   // 6400000

typedef unsigned short ushortT;
typedef __bf16 bf16_t;
typedef bf16_t bf16x8 __attribute__((ext_vector_type(8)));
typedef float f32x4 __attribute__((ext_vector_type(4)));

__device__ __forceinline__ ushortT f2bf(float f) {
  union { float f; unsigned u; } v; v.f = f;
  unsigned u = v.u;
  u += 0x7fffu + ((u >> 16) & 1u);
  return (ushortT)(u >> 16);
}
__device__ __forceinline__ float fsig(float x) { return 1.0f / (1.0f + __expf(-x)); }
__device__ __forceinline__ float ftanh(float x) {
  float e = __expf(2.0f * x);
  return 1.0f - 2.0f / (e + 1.0f);
}
#define PIN(v) asm volatile("" : "+v"(v))

// Workgroup barrier WITHOUT the vmcnt(0) drain __syncthreads emits.
// LDS producer->consumer ordering needs lgkmcnt(0) only.
__device__ __forceinline__ void bar_sync() {
  asm volatile("s_waitcnt lgkmcnt(0)\n\ts_barrier" ::: "memory");
  __builtin_amdgcn_sched_barrier(0);
}

// ---------------------------------------------------------------------------
// Weight prep: Wcat1 [256][128] = [wih1(62,pad2) | whh1(64)]
//              Wcat2 [512][192] = [wih2(64) | whh2(128)]
//              Wcat3 [1024][384] = [wih3(128) | whh3(256)]   (bf16, row = gate)
// ---------------------------------------------------------------------------
__global__ void k_wprep(const float* __restrict__ w1i, const float* __restrict__ w1h,
                        const float* __restrict__ w2i, const float* __restrict__ w2h,
                        const float* __restrict__ w3i, const float* __restrict__ w3h,
                        ushortT* __restrict__ Wcat) {
  int id = blockIdx.x * 256 + threadIdx.x;
  if (id >= 524288) return;
  float v;
  if (id < 32768) {
    int g = id >> 7, k = id & 127;
    v = (k < 62) ? w1i[g * 62 + k] : ((k >= 64) ? w1h[g * 64 + (k - 64)] : 0.0f);
  } else if (id < 131072) {
    int j = id - 32768; int g = j / 192, k = j % 192;
    v = (k < 64) ? w2i[g * 64 + k] : w2h[g * 128 + (k - 64)];
  } else {
    int j = id - 131072; int g = j / 384, k = j % 384;
    v = (k < 128) ? w3i[g * 128 + k] : w3h[g * 256 + (k - 128)];
  }
  Wcat[id] = f2bf(v);
}

// x [N][F][T] -> xt [T][N][F], LDS-tiled per node row
__global__ void k_transpose(const float* __restrict__ x, float* __restrict__ xt) {
  __shared__ float s[528];  // 16 x 33
  int n = blockIdx.x;
  int tid = threadIdx.x;
  for (int i = tid; i < 512; i += 256) {
    s[(i >> 5) * 33 + (i & 31)] = x[(size_t)n * 512 + i];
  }
  __syncthreads();
  for (int i = tid; i < 512; i += 256) {
    int t = i >> 4, f = i & 15;
    xt[((size_t)t * NNODE + n) * 16 + f] = s[f * 33 + t];
  }
}

// per-edge: deg[src] += w ; counts[dst] += 1
__global__ void k_degcount(const int* __restrict__ ei, const float* __restrict__ ew,
                           float* __restrict__ deg, int* __restrict__ counts) {
  int id = blockIdx.x * 256 + threadIdx.x;
  if (id >= TE) return;
  int t = id / EDGES, e = id % EDGES;
  int src = ei[(2 * t) * EDGES + e];
  int dst = ei[(2 * t + 1) * EDGES + e];
  atomicAdd(&deg[t * NNODE + src], ew[id]);
  atomicAdd(&counts[t * NNODE + dst], 1);
}

__global__ void k_dinv(float* __restrict__ deg) {
  int id = blockIdx.x * 256 + threadIdx.x;
  if (id >= TN) return;
  float d = deg[id];
  deg[id] = (d > 0.0f) ? rsqrtf(d) : 0.0f;
}

// block-local exclusive scan of counts (256-chunks), chunk totals out
__global__ void k_scanA(const int* __restrict__ counts, int* __restrict__ offs,
                        int* __restrict__ ctot) {
  __shared__ int s[256];
  int tid = threadIdx.x;
  int gid = blockIdx.x * 256 + tid;
  int v = counts[gid];
  s[tid] = v; __syncthreads();
  for (int off = 1; off < 256; off <<= 1) {
    int x = (tid >= off) ? s[tid - off] : 0;
    __syncthreads();
    s[tid] += x;
    __syncthreads();
  }
  offs[gid] = s[tid] - v;
  if (tid == 255) ctot[blockIdx.x] = s[255];
}

// single-block scan of 1984 chunk totals
__global__ void k_scanB(const int* __restrict__ ctot, int* __restrict__ cbase) {
  __shared__ int s[256];
  int tid = threadIdx.x;
  int carry = 0;
  for (int c = 0; c < 8; ++c) {
    int i = c * 256 + tid;
    int v = (i < 1984) ? ctot[i] : 0;
    s[tid] = v; __syncthreads();
    for (int off = 1; off < 256; off <<= 1) {
      int x = (tid >= off) ? s[tid - off] : 0;
      __syncthreads();
      s[tid] += x;
      __syncthreads();
    }
    if (i < 1984) cbase[i] = carry + s[tid] - v;
    int tot = s[255];
    __syncthreads();
    carry += tot;
  }
}

__global__ void k_scanC(int* __restrict__ offs, const int* __restrict__ cbase) {
  int id = blockIdx.x * 256 + threadIdx.x;
  if (id >= TN) return;
  offs[id] += cbase[id >> 8];
}

// scatter edges into CSR slots: csr_src[pos], csr_nrm[pos]
__global__ void k_fill(const int* __restrict__ ei, const float* __restrict__ ew,
                       const float* __restrict__ dinv, const int* __restrict__ offs,
                       int* __restrict__ fillc, int* __restrict__ csrs,
                       float* __restrict__ csrn) {
  int id = blockIdx.x * 256 + threadIdx.x;
  if (id >= TE) return;
  int t = id / EDGES, e = id % EDGES;
  int src = ei[(2 * t) * EDGES + e];
  int dst = ei[(2 * t + 1) * EDGES + e];
  int idx = t * NNODE + dst;
  int pos = offs[idx] + atomicAdd(&fillc[idx], 1);
  csrs[pos] = src;
  csrn[pos] = -dinv[t * NNODE + src] * ew[id] * dinv[idx];
}

__device__ __forceinline__ void fma4(float4& a, float sc, const float4 b) {
  a.x += sc * b.x; a.y += sc * b.y; a.z += sc * b.z; a.w += sc * b.w;
}

// gather (tx1) + combine: out = x@w0 + tx1@w1 + b [+leaky] ; mode1 writes xc bf16
__global__ void k_gc(const float* __restrict__ in, const int* __restrict__ offs,
                     const int* __restrict__ csrs, const float* __restrict__ csrn,
                     const float* __restrict__ w0, const float* __restrict__ w1,
                     const float* __restrict__ bias, float* __restrict__ outF,
                     ushortT* __restrict__ outX, int mode) {
  __shared__ float sw0[256], sw1[256], sb[16];
  int tid = threadIdx.x;
  sw0[tid] = w0[tid];
  sw1[tid] = w1[tid];
  if (tid < 16) sb[tid] = bias[tid];
  __syncthreads();
  int idx = blockIdx.x * 256 + tid;
  if (idx >= TN) return;
  int t = idx / NNODE, n = idx % NNODE;
  const float4* rowp = (const float4*)(in + (size_t)idx * 16);
  float4 x0 = rowp[0], x1 = rowp[1], x2 = rowp[2], x3 = rowp[3];
  float4 a0 = {0, 0, 0, 0}, a1 = {0, 0, 0, 0}, a2 = {0, 0, 0, 0}, a3 = {0, 0, 0, 0};
  int beg = offs[idx];
  int end = (idx == TN - 1) ? TE : offs[idx + 1];
  const float* base = in + (size_t)t * NNODE * 16;
  for (int p2 = beg; p2 < end; ++p2) {
    int s = csrs[p2];
    float nr = csrn[p2];
    const float4* rp = (const float4*)(base + (size_t)s * 16);
    fma4(a0, nr, rp[0]); fma4(a1, nr, rp[1]); fma4(a2, nr, rp[2]); fma4(a3, nr, rp[3]);
  }
  float xr[16], ar[16];
  *(float4*)&xr[0] = x0; *(float4*)&xr[4] = x1; *(float4*)&xr[8] = x2; *(float4*)&xr[12] = x3;
  *(float4*)&ar[0] = a0; *(float4*)&ar[4] = a1; *(float4*)&ar[8] = a2; *(float4*)&ar[12] = a3;
  float o[16];
#pragma unroll
  for (int j = 0; j < 16; ++j) o[j] = sb[j];
#pragma unroll
  for (int k = 0; k < 16; ++k) {
    float xv = xr[k], av = ar[k];
#pragma unroll
    for (int j = 0; j < 16; ++j) o[j] += xv * sw0[k * 16 + j] + av * sw1[k * 16 + j];
  }
  if (mode == 0) {
#pragma unroll
    for (int j = 0; j < 16; ++j) o[j] = (o[j] > 0.0f) ? o[j] : 0.01f * o[j];
    float4* op = (float4*)(outF + (size_t)idx * 16);
    op[0] = *(float4*)&o[0]; op[1] = *(float4*)&o[4];
    op[2] = *(float4*)&o[8]; op[3] = *(float4*)&o[12];
  } else {
    int bb = n / 62, ch = n % 62;
#pragma unroll
    for (int j = 0; j < 16; ++j)
      outX[((size_t)(bb * 512 + t * 16 + j)) * 64 + ch] = f2bf(o[j]);
  }
}

// ---------------------------------------------------------------------------
// FUSED LSTM: 48 blocks x 512 thr, 1 block/CU.
//   bx 0..15  = A-role: layers 1+2 for group g=bx. Writes h2(t) as tagged
//               u32 ((t+1)<<16 | bf16) to h2x[g][t][2048], relaxed agent.
//               Self-validating words -> no fences, cross-XCD safe.
//   bx 16..47 = B-role: layer 3, block (g,s) computes cols [s*128,(s+1)*128).
//               Polls h2x slot t+1 (issued top-of-step, checked after
//               phase B -> full-step latency tolerance) into LDS H2S.
//               Partner h3 exchange via xbuf (unchanged R10 scheme).
// A never waits on B; A step < B step -> pipeline hides all of lstmA.
// ---------------------------------------------------------------------------
__global__ __launch_bounds__(512, 1) void k_lstm(const ushortT* __restrict__ xc,
                                                 const ushortT* __restrict__ Wcat,
                                                 const float* __restrict__ b1g,
                                                 const float* __restrict__ b2g,
                                                 const float* __restrict__ b3g,
                                                 ushortT* __restrict__ zbuf,
                                                 uint32_t* __restrict__ h2x,
                                                 uint32_t* __restrict__ xbuf) {
  // A-role LDS
  __shared__ ushortT X1[2][16 * 72];
  __shared__ ushortT H1[2][16 * 72];
  __shared__ ushortT H2[2][16 * 136];
  // B-role LDS
  __shared__ ushortT HS[2][16 * 136];
  __shared__ ushortT PS[2][16 * 136];
  __shared__ ushortT H2S[2][16 * 136];
  int tid = threadIdx.x;
  int wv = tid >> 6, lane = tid & 63;
  int col = lane & 15, koff = (lane >> 4) * 8, m = lane & 15;
  int bx = blockIdx.x;

  if (bx < 16) {
    // ===================== A-role: layers 1+2 =====================
    int g = bx;
    int bg = g * 16;
    const ushortT* W1 = Wcat;
    const ushortT* W2 = Wcat + 32768;

    bf16x8 w1r[4][4];
    if (wv < 4) {
#pragma unroll
      for (int q = 0; q < 4; ++q)
#pragma unroll
        for (int k = 0; k < 4; ++k) {
          w1r[q][k] = *reinterpret_cast<const bf16x8*>(
              &W1[(size_t)(q * 64 + wv * 16 + col) * 128 + k * 32 + koff]);
          PIN(w1r[q][k]);
        }
    }
    bf16x8 w2r[4][6];
#pragma unroll
    for (int q = 0; q < 4; ++q)
#pragma unroll
      for (int k = 0; k < 6; ++k) {
        w2r[q][k] = *reinterpret_cast<const bf16x8*>(
            &W2[(size_t)(q * 128 + wv * 16 + col) * 192 + k * 32 + koff]);
        PIN(w2r[q][k]);
      }
    float b1v[4] = {0, 0, 0, 0}, b2v[4];
    if (wv < 4) {
#pragma unroll
      for (int q = 0; q < 4; ++q) b1v[q] = b1g[q * 64 + wv * 16 + col];
    }
#pragma unroll
    for (int q = 0; q < 4; ++q) b2v[q] = b2g[q * 128 + wv * 16 + col];

    float c1r[4] = {0, 0, 0, 0};
    float c2r[4] = {0, 0, 0, 0};

    for (int i = tid; i < 2 * 16 * 72; i += 512) { X1[0][i] = 0; H1[0][i] = 0; }
    for (int i = tid; i < 2 * 16 * 136; i += 512) H2[0][i] = 0;
    __syncthreads();
    // prestage xc(t=0) + prefetch xc(t=1) into regs (waves 4-5)
    uint4 xreg = {0, 0, 0, 0};
    {
      int tid2 = tid - 256;
      if (tid2 >= 0 && tid2 < 128) {
        int mm = tid2 >> 3, jj = (tid2 & 7) * 8;
        *(uint4*)&X1[0][mm * 72 + jj] =
            *(const uint4*)&xc[((size_t)(bg + mm) * 512 + 0) * 64 + jj];
        xreg = *(const uint4*)&xc[((size_t)(bg + mm) * 512 + 1) * 64 + jj];
      }
    }
    __syncthreads();

    uint32_t* h2g = h2x + (size_t)g * 512 * 2048;

    for (int t = 0; t < 512; ++t) {
      int pr = t & 1, pw = 1 - pr;
      if (wv < 4) {
        // L1: K = 64 x | 64 h1
        f32x4 acc[4] = {};
#pragma unroll
        for (int kt = 0; kt < 4; ++kt) {
          const ushortT* ap = (kt < 2) ? &X1[pr][m * 72 + kt * 32 + koff]
                                       : &H1[pr][m * 72 + (kt - 2) * 32 + koff];
          bf16x8 a = *reinterpret_cast<const bf16x8*>(ap);
#pragma unroll
          for (int q = 0; q < 4; ++q)
            acc[q] = __builtin_amdgcn_mfma_f32_16x16x32_bf16(a, w1r[q][kt], acc[q], 0, 0, 0);
        }
#pragma unroll
        for (int r = 0; r < 4; ++r) {
          int row = (lane >> 4) * 4 + r;
          int lc = wv * 16 + col;
          float gi = acc[0][r] + b1v[0];
          float gf = acc[1][r] + b1v[1];
          float gg = acc[2][r] + b1v[2];
          float go = acc[3][r] + b1v[3];
          float c = fsig(gf) * c1r[r] + fsig(gi) * ftanh(gg);
          float h = fsig(go) * ftanh(c);
          c1r[r] = c;
          H1[pw][row * 72 + lc] = f2bf(h);
        }
      } else {
        // waves 4-5: ds_write xc(t+1) from regs, issue load for xc(t+2)
        int tid2 = tid - 256;
        if (tid2 < 128) {
          int mm = tid2 >> 3, jj = (tid2 & 7) * 8;
          if (t + 1 < 512)
            *(uint4*)&X1[pw][mm * 72 + jj] = xreg;
          int tf = (t + 2 < 512) ? t + 2 : 511;
          xreg = *(const uint4*)&xc[((size_t)(bg + mm) * 512 + tf) * 64 + jj];
        }
      }
      bar_sync();
      // L2: K = 64 h1(t) | 128 h2(t-1)
      {
        f32x4 acc[4] = {};
#pragma unroll
        for (int kt = 0; kt < 6; ++kt) {
          const ushortT* ap = (kt < 2) ? &H1[pw][m * 72 + kt * 32 + koff]
                                       : &H2[pr][m * 136 + (kt - 2) * 32 + koff];
          bf16x8 a = *reinterpret_cast<const bf16x8*>(ap);
#pragma unroll
          for (int q = 0; q < 4; ++q)
            acc[q] = __builtin_amdgcn_mfma_f32_16x16x32_bf16(a, w2r[q][kt], acc[q], 0, 0, 0);
        }
        uint32_t tag = ((uint32_t)(t + 1)) << 16;
#pragma unroll
        for (int r = 0; r < 4; ++r) {
          int row = (lane >> 4) * 4 + r;
          int lc = wv * 16 + col;
          float gi = acc[0][r] + b2v[0];
          float gf = acc[1][r] + b2v[1];
          float gg = acc[2][r] + b2v[2];
          float go = acc[3][r] + b2v[3];
          float c = fsig(gf) * c2r[r] + fsig(gi) * ftanh(gg);
          float h = fsig(go) * ftanh(c);
          c2r[r] = c;
          ushortT hb = f2bf(h);
          H2[pw][row * 136 + lc] = hb;
          // tagged publish to B-consumers (self-validating word)
          __hip_atomic_store(&h2g[(size_t)t * 2048 + row * 128 + lc], tag | hb,
                             __ATOMIC_RELAXED, __HIP_MEMORY_SCOPE_AGENT);
        }
      }
      bar_sync();
    }
  } else {
    // ===================== B-role: layer 3 =====================
    int bxx = bx - 16;
    int s = (bxx >> 3) & 1;
    int g = (bxx & 7) | ((bxx >> 4) << 3);
    int ps = 1 - s;
    int bg = g * 16;
    const ushortT* W3 = Wcat + 131072;

    bf16x8 wH[4][4], wO[4][4], wP[4][4];
#pragma unroll
    for (int q = 0; q < 4; ++q) {
      const ushortT* rw = &W3[(size_t)(q * 256 + s * 128 + wv * 16 + col) * 384];
#pragma unroll
      for (int j = 0; j < 4; ++j) {
        wH[q][j] = *reinterpret_cast<const bf16x8*>(&rw[j * 32 + koff]);
        wO[q][j] = *reinterpret_cast<const bf16x8*>(&rw[(4 + s * 4 + j) * 32 + koff]);
        wP[q][j] = *reinterpret_cast<const bf16x8*>(&rw[(4 + ps * 4 + j) * 32 + koff]);
        PIN(wH[q][j]); PIN(wO[q][j]); PIN(wP[q][j]);
      }
    }
    float b3v[4];
#pragma unroll
    for (int q = 0; q < 4; ++q) b3v[q] = b3g[q * 256 + s * 128 + wv * 16 + col];

    float c3r[4] = {0, 0, 0, 0};

    for (int i = tid; i < 2 * 16 * 136; i += 512) HS[0][i] = 0;
    __syncthreads();

    // xbuf layout: [g][half][parity][16 rows][128 cols] u32
    uint32_t* myslot = xbuf + (((size_t)g * 2 + s) * 2) * 2048;
    const uint32_t* pslot = xbuf + (((size_t)g * 2 + ps) * 2) * 2048;
    const uint32_t* h2g = h2x + (size_t)g * 512 * 2048;

    int prow = tid >> 5, pc0 = (tid & 31) * 4;

    // prologue: poll h2(0) (tag 1) into H2S[0]
    {
      const uint32_t* hp = h2g + prow * 128 + pc0;
      uint32_t u0 = __hip_atomic_load(hp + 0, __ATOMIC_RELAXED, __HIP_MEMORY_SCOPE_AGENT);
      uint32_t u1 = __hip_atomic_load(hp + 1, __ATOMIC_RELAXED, __HIP_MEMORY_SCOPE_AGENT);
      uint32_t u2 = __hip_atomic_load(hp + 2, __ATOMIC_RELAXED, __HIP_MEMORY_SCOPE_AGENT);
      uint32_t u3 = __hip_atomic_load(hp + 3, __ATOMIC_RELAXED, __HIP_MEMORY_SCOPE_AGENT);
      for (;;) {
        bool ok = ((u0 >> 16) == 1u) & ((u1 >> 16) == 1u) &
                  ((u2 >> 16) == 1u) & ((u3 >> 16) == 1u);
        if (ok) break;
        u0 = __hip_atomic_load(hp + 0, __ATOMIC_RELAXED, __HIP_MEMORY_SCOPE_AGENT);
        u1 = __hip_atomic_load(hp + 1, __ATOMIC_RELAXED, __HIP_MEMORY_SCOPE_AGENT);
        u2 = __hip_atomic_load(hp + 2, __ATOMIC_RELAXED, __HIP_MEMORY_SCOPE_AGENT);
        u3 = __hip_atomic_load(hp + 3, __ATOMIC_RELAXED, __HIP_MEMORY_SCOPE_AGENT);
      }
      H2S[0][prow * 136 + pc0 + 0] = (ushortT)(u0 & 0xffffu);
      H2S[0][prow * 136 + pc0 + 1] = (ushortT)(u1 & 0xffffu);
      H2S[0][prow * 136 + pc0 + 2] = (ushortT)(u2 & 0xffffu);
      H2S[0][prow * 136 + pc0 + 3] = (ushortT)(u3 & 0xffffu);
    }
    __syncthreads();

    for (int t = 0; t < 512; ++t) {
      int prt = t & 1, pw = 1 - prt;
      // issue partner xbuf poll loads (latency hides under phaseA+own)
      const uint32_t* pb = pslot + (size_t)prt * 2048 + prow * 128 + pc0;
      uint32_t v0 = 0, v1 = 0, v2 = 0, v3 = 0;
      if (t > 0) {
        v0 = __hip_atomic_load(pb + 0, __ATOMIC_RELAXED, __HIP_MEMORY_SCOPE_AGENT);
        v1 = __hip_atomic_load(pb + 1, __ATOMIC_RELAXED, __HIP_MEMORY_SCOPE_AGENT);
        v2 = __hip_atomic_load(pb + 2, __ATOMIC_RELAXED, __HIP_MEMORY_SCOPE_AGENT);
        v3 = __hip_atomic_load(pb + 3, __ATOMIC_RELAXED, __HIP_MEMORY_SCOPE_AGENT);
      }
      // issue h2x poll loads for slot t+1 (tag t+2); checked after phase B
      const uint32_t* hp = h2g + (size_t)(t + 1) * 2048 + prow * 128 + pc0;
      uint32_t u0 = 0, u1 = 0, u2 = 0, u3 = 0;
      if (t < 511) {
        u0 = __hip_atomic_load(hp + 0, __ATOMIC_RELAXED, __HIP_MEMORY_SCOPE_AGENT);
        u1 = __hip_atomic_load(hp + 1, __ATOMIC_RELAXED, __HIP_MEMORY_SCOPE_AGENT);
        u2 = __hip_atomic_load(hp + 2, __ATOMIC_RELAXED, __HIP_MEMORY_SCOPE_AGENT);
        u3 = __hip_atomic_load(hp + 3, __ATOMIC_RELAXED, __HIP_MEMORY_SCOPE_AGENT);
      }
      __builtin_amdgcn_sched_barrier(0);
      f32x4 acc[4] = {};
      // phase A: h2(t) from LDS H2S[prt]
#pragma unroll
      for (int kt = 0; kt < 4; ++kt) {
        bf16x8 a = *reinterpret_cast<const bf16x8*>(&H2S[prt][m * 136 + kt * 32 + koff]);
#pragma unroll
        for (int q = 0; q < 4; ++q)
          acc[q] = __builtin_amdgcn_mfma_f32_16x16x32_bf16(a, wH[q][kt], acc[q], 0, 0, 0);
      }
      if (t > 0) {
        // own h3 half (from LDS HS)
#pragma unroll
        for (int j = 0; j < 4; ++j) {
          bf16x8 a = *reinterpret_cast<const bf16x8*>(&HS[prt][m * 136 + j * 32 + koff]);
#pragma unroll
          for (int q = 0; q < 4; ++q)
            acc[q] = __builtin_amdgcn_mfma_f32_16x16x32_bf16(a, wO[q][j], acc[q], 0, 0, 0);
        }
        // check partner tags -> PS
        {
          uint32_t want = (uint32_t)t;
          while (((v0 >> 16) != want) | ((v1 >> 16) != want) |
                 ((v2 >> 16) != want) | ((v3 >> 16) != want)) {
            v0 = __hip_atomic_load(pb + 0, __ATOMIC_RELAXED, __HIP_MEMORY_SCOPE_AGENT);
            v1 = __hip_atomic_load(pb + 1, __ATOMIC_RELAXED, __HIP_MEMORY_SCOPE_AGENT);
            v2 = __hip_atomic_load(pb + 2, __ATOMIC_RELAXED, __HIP_MEMORY_SCOPE_AGENT);
            v3 = __hip_atomic_load(pb + 3, __ATOMIC_RELAXED, __HIP_MEMORY_SCOPE_AGENT);
          }
          PS[prt][prow * 136 + pc0 + 0] = (ushortT)(v0 & 0xffffu);
          PS[prt][prow * 136 + pc0 + 1] = (ushortT)(v1 & 0xffffu);
          PS[prt][prow * 136 + pc0 + 2] = (ushortT)(v2 & 0xffffu);
          PS[prt][prow * 136 + pc0 + 3] = (ushortT)(v3 & 0xffffu);
        }
        bar_sync();
        // phase B: partner h3 half from PS
#pragma unroll
        for (int j = 0; j < 4; ++j) {
          bf16x8 a = *reinterpret_cast<const bf16x8*>(&PS[prt][m * 136 + j * 32 + koff]);
#pragma unroll
          for (int q = 0; q < 4; ++q)
            acc[q] = __builtin_amdgcn_mfma_f32_16x16x32_bf16(a, wP[q][j], acc[q], 0, 0, 0);
        }
      }
      // check h2(t+1) tags -> H2S[pw] (consumed next step after barrier)
      if (t < 511) {
        uint32_t want = (uint32_t)(t + 2);
        while (((u0 >> 16) != want) | ((u1 >> 16) != want) |
               ((u2 >> 16) != want) | ((u3 >> 16) != want)) {
          u0 = __hip_atomic_load(hp + 0, __ATOMIC_RELAXED, __HIP_MEMORY_SCOPE_AGENT);
          u1 = __hip_atomic_load(hp + 1, __ATOMIC_RELAXED, __HIP_MEMORY_SCOPE_AGENT);
          u2 = __hip_atomic_load(hp + 2, __ATOMIC_RELAXED, __HIP_MEMORY_SCOPE_AGENT);
          u3 = __hip_atomic_load(hp + 3, __ATOMIC_RELAXED, __HIP_MEMORY_SCOPE_AGENT);
        }
        H2S[pw][prow * 136 + pc0 + 0] = (ushortT)(u0 & 0xffffu);
        H2S[pw][prow * 136 + pc0 + 1] = (ushortT)(u1 & 0xffffu);
        H2S[pw][prow * 136 + pc0 + 2] = (ushortT)(u2 & 0xffffu);
        H2S[pw][prow * 136 + pc0 + 3] = (ushortT)(u3 & 0xffffu);
      }
      // epilogue: gates -> c,h ; xbuf tag stores, publish, HS/zbuf
      uint32_t* mw = myslot + (size_t)((t + 1) & 1) * 2048;
      ushortT hbs[4];
#pragma unroll
      for (int r = 0; r < 4; ++r) {
        int row = (lane >> 4) * 4 + r;
        int lc = wv * 16 + col;
        float gi = acc[0][r] + b3v[0];
        float gf = acc[1][r] + b3v[1];
        float gg = acc[2][r] + b3v[2];
        float go = acc[3][r] + b3v[3];
        float c = fsig(gf) * c3r[r] + fsig(gi) * ftanh(gg);
        float h = fsig(go) * ftanh(c);
        c3r[r] = c;
        hbs[r] = f2bf(h);
        __hip_atomic_store(mw + row * 128 + lc, ((uint32_t)(t + 1) << 16) | hbs[r],
                           __ATOMIC_RELAXED, __HIP_MEMORY_SCOPE_AGENT);
      }
      asm volatile("s_waitcnt vmcnt(0)" ::: "memory");
      __builtin_amdgcn_sched_barrier(0);
#pragma unroll
      for (int r = 0; r < 4; ++r) {
        int row = (lane >> 4) * 4 + r;
        int lc = wv * 16 + col;
        HS[pw][row * 136 + lc] = hbs[r];
        zbuf[((size_t)(bg + row) * 512 + t) * 256 + s * 128 + lc] = hbs[r];
      }
      bar_sync();
    }
  }
}

// ---------------------------------------------------------------------------
// fc1: split-K MFMA. grid (kb=64, nb=4); block computes [256m x 64n] partial
// over a 2048-K chunk; W transposed fp32->bf16 through LDS.
// ---------------------------------------------------------------------------
__global__ __launch_bounds__(256) void k_fc1(const ushortT* __restrict__ zbuf,
                                             const float* __restrict__ w,
                                             float* __restrict__ part) {
  __shared__ ushortT As[256 * 40];
  __shared__ ushortT Bs[64 * 40];
  int tid = threadIdx.x;
  int kb = blockIdx.x;  // 0..63
  int nb = blockIdx.y;  // 0..3
  int wv = tid >> 6, lane = tid & 63;
  int col = lane & 15, koff = (lane >> 4) * 8;
  int k0base = kb * 2048;
  f32x4 acc[4][4] = {};
  for (int kt = 0; kt < 64; ++kt) {
    int k0 = k0base + kt * 32;
    {
      const uint4* src = (const uint4*)(zbuf + (size_t)tid * 131072 + k0);
      uint4* dst = (uint4*)(As + tid * 40);
      dst[0] = src[0]; dst[1] = src[1]; dst[2] = src[2]; dst[3] = src[3];
    }
    {
      int kk = tid >> 3, j0 = (tid & 7) * 8;
      const float* srcw = w + (size_t)(k0 + kk) * 256 + nb * 64 + j0;
#pragma unroll
      for (int jj = 0; jj < 8; ++jj) Bs[(j0 + jj) * 40 + kk] = f2bf(srcw[jj]);
    }
    __syncthreads();
    bf16x8 bfr[4];
#pragma unroll
    for (int nt = 0; nt < 4; ++nt)
      bfr[nt] = *reinterpret_cast<const bf16x8*>(&Bs[(nt * 16 + col) * 40 + koff]);
#pragma unroll
    for (int mt = 0; mt < 4; ++mt) {
      bf16x8 afr = *reinterpret_cast<const bf16x8*>(&As[(wv * 64 + mt * 16 + col) * 40 + koff]);
#pragma unroll
      for (int nt = 0; nt < 4; ++nt)
        acc[mt][nt] = __builtin_amdgcn_mfma_f32_16x16x32_bf16(afr, bfr[nt], acc[mt][nt], 0, 0, 0);
    }
    __syncthreads();
  }
#pragma unroll
  for (int mt = 0; mt < 4; ++mt)
#pragma unroll
    for (int nt = 0; nt < 4; ++nt)
#pragma unroll
      for (int r = 0; r < 4; ++r) {
        int m = wv * 64 + mt * 16 + (lane >> 4) * 4 + r;
        int n = nb * 64 + nt * 16 + col;
        part[(size_t)kb * 65536 + m * 256 + n] = acc[mt][nt][r];
      }
}

__global__ void k_fc1red(const float* __restrict__ part, const float* __restrict__ b,
                         float* __restrict__ out) {
  int id = blockIdx.x * 256 + threadIdx.x;
  if (id >= 65536) return;
  float s = 0.0f;
  for (int kb = 0; kb < 64; ++kb) s += part[(size_t)kb * 65536 + id];
  s += b[id & 255];
  out[id] = fmaxf(s, 0.0f);
}

__global__ void k_fcv(const float* __restrict__ in, const float* __restrict__ w,
                      const float* __restrict__ b, float* __restrict__ out,
                      int K, int Nn, int doRelu) {
  int id = blockIdx.x * 256 + threadIdx.x;
  int m = id / Nn, n = id % Nn;
  float s = b[n];
  for (int k = 0; k < K; ++k) s += in[m * K + k] * w[k * Nn + n];
  if (doRelu) s = fmaxf(s, 0.0f);
  out[id] = s;
}

// ---------------------------------------------------------------------------
extern "C" void kernel_launch(void* const* d_in, const int* in_sizes, int n_in,
                              void* d_out, int out_size, void* d_ws, size_t ws_size,
                              hipStream_t stream) {
  (void)in_sizes; (void)n_in; (void)out_size; (void)ws_size;
  const float* x    = (const float*)d_in[0];
  const int* ei     = (const int*)d_in[1];
  const float* ew   = (const float*)d_in[2];
  const float* c1w0 = (const float*)d_in[4];
  const float* c1w1 = (const float*)d_in[5];
  const float* c1b  = (const float*)d_in[6];
  const float* c2w0 = (const float*)d_in[7];
  const float* c2w1 = (const float*)d_in[8];
  const float* c2b  = (const float*)d_in[9];
  const float* l1wi = (const float*)d_in[10];
  const float* l1wh = (const float*)d_in[11];
  const float* l1b  = (const float*)d_in[12];
  const float* l2wi = (const float*)d_in[13];
  const float* l2wh = (const float*)d_in[14];
  const float* l2b  = (const float*)d_in[15];
  const float* l3wi = (const float*)d_in[16];
  const float* l3wh = (const float*)d_in[17];
  const float* l3b  = (const float*)d_in[18];
  const float* fc1w = (const float*)d_in[19];
  const float* fc1b = (const float*)d_in[20];
  const float* fc2w = (const float*)d_in[21];
  const float* fc2b = (const float*)d_in[22];
  const float* fc3w = (const float*)d_in[23];
  const float* fc3b = (const float*)d_in[24];
  const float* fc4w = (const float*)d_in[25];
  const float* fc4b = (const float*)d_in[26];
  float* out = (float*)d_out;

  char* p = (char*)d_ws;
  auto alloc = [&](size_t bytes) { void* r = (void*)p; p += (bytes + 255) & ~(size_t)255; return r; };
  float* xt      = (float*)alloc(32505856);    // [T][N][16]  (reused as h2x)
  float* h1buf   = (float*)alloc(32505856);    // conv1 out   (part of reuse window)
  float* dinv    = (float*)alloc(2031616);     // deg -> rsqrt in place (reuse window)
  int* counts    = (int*)alloc(2031616);       // (reuse window tail)
  int* offs      = (int*)alloc(2031616);
  int* fillc     = (int*)alloc(2031616);
  int* ctot      = (int*)alloc(8192);
  int* cbase     = (int*)alloc(8192);
  int* csrs      = (int*)alloc(25600000);
  float* csrn    = (float*)alloc(25600000);
  ushortT* xc    = (ushortT*)alloc(16777216);  // [B][512][64] bf16 (pad 62->64)
  ushortT* Wcat  = (ushortT*)alloc(1048576);
  ushortT* zbuf  = (ushortT*)alloc(67108864);  // [B][512][256] bf16
  float* part    = (float*)alloc(16777216);    // fc1 partials [64][256][256]
  float* fo1     = (float*)alloc(262144);
  float* fo2     = (float*)alloc(131072);
  float* fo3     = (float*)alloc(65536);
  uint32_t* xbuf = (uint32_t*)alloc(524288);   // [16][2][2 parity][2048] u32
  // h2x [16 g][512 t][2048] u32 = 64 MB, aliased over xt+h1buf+dinv+counts
  // (69.1 MB window, all dead after the k_gc pair / scans). memset-0 below
  // guarantees stale data can't collide with tags 1..512.
  uint32_t* h2x = (uint32_t*)xt;

  hipMemsetAsync(dinv, 0, 2031616, stream);
  hipMemsetAsync(counts, 0, 2031616, stream);
  hipMemsetAsync(fillc, 0, 2031616, stream);
  hipMemsetAsync(xc, 0, 16777216, stream);
  // xbuf needs no init: harness poisons d_ws with 0xAA -> tag 0xAAAA never
  // matches any live tag (1..512).

  k_wprep<<<2048, 256, 0, stream>>>(l1wi, l1wh, l2wi, l2wh, l3wi, l3wh, Wcat);
  k_transpose<<<15872, 256, 0, stream>>>(x, xt);
  k_degcount<<<25000, 256, 0, stream>>>(ei, ew, dinv, counts);
  k_dinv<<<1984, 256, 0, stream>>>(dinv);
  k_scanA<<<1984, 256, 0, stream>>>(counts, offs, ctot);
  k_scanB<<<1, 256, 0, stream>>>(ctot, cbase);
  k_scanC<<<1984, 256, 0, stream>>>(offs, cbase);
  k_fill<<<25000, 256, 0, stream>>>(ei, ew, dinv, offs, fillc, csrs, csrn);
  k_gc<<<1984, 256, 0, stream>>>(xt, offs, csrs, csrn, c1w0, c1w1, c1b, h1buf, nullptr, 0);
  k_gc<<<1984, 256, 0, stream>>>(h1buf, offs, csrs, csrn, c2w0, c2w1, c2b, nullptr, xc, 1);
  // clear tag space before fused LSTM (xt/h1buf/dinv/counts are dead now)
  hipMemsetAsync(h2x, 0, 67108864, stream);
  k_lstm<<<48, 512, 0, stream>>>(xc, Wcat, l1b, l2b, l3b, zbuf, h2x, xbuf);
  k_fc1<<<dim3(64, 4), 256, 0, stream>>>(zbuf, fc1w, part);
  k_fc1red<<<256, 256, 0, stream>>>(part, fc1b, fo1);
  k_fcv<<<128, 256, 0, stream>>>(fo1, fc2w, fc2b, fo2, 256, 128, 1);
  k_fcv<<<64, 256, 0, stream>>>(fo2, fc3w, fc3b, fo3, 128, 64, 1);
  k_fcv<<<4, 256, 0, stream>>>(fo3, fc4w, fc4b, out, 64, 4, 0);
}